// Round 10
// baseline (1173.021 us; speedup 1.0000x reference)
//
#include <hip/hip_runtime.h>
#include <hip/hip_bf16.h>
#include <cstdint>

#define B_  8
#define T_  16
#define HIN 640
#define WIN 480
#define HP  320
#define WP  240
#define HO  318
#define WO  238

typedef unsigned short u16;
typedef unsigned int   u32;
typedef __attribute__((ext_vector_type(8))) short bf16x8;
typedef __attribute__((ext_vector_type(4))) float f32x4;

#define TY    4
#define PITCH 24    // halfwords per pixel slot (48 B): b128-aligned, ~2-way banks
#define NFRAG 25    // 20 hi (q0..4 x nt0..3) + 5 lo (nt=2 only, q0..4)
#define NSLOT 384   // x A-frag slots (6 rows x 64 cols) for step-1
#define CPX   62    // core output cols per x-tile (step-2)

__device__ __forceinline__ u16 f2bf(float f) {          // RNE float->bf16 bits
    u32 u = __float_as_uint(f);
    return (u16)((u + 0x7fffu + ((u >> 16) & 1u)) >> 16);
}
__device__ __forceinline__ float bf2f(u16 u) {
    return __uint_as_float(((u32)u) << 16);
}
__device__ __forceinline__ float h2f(u16 u) {           // fp16 bits -> f32
    _Float16 h = __builtin_bit_cast(_Float16, u);
    return (float)h;
}
__device__ __forceinline__ u16 f2h(float f) {           // f32 -> fp16 bits
    _Float16 h = (_Float16)f;
    return __builtin_bit_cast(u16, h);
}
__device__ __forceinline__ float hsg(float v) {         // med3 clamp
    return __builtin_amdgcn_fmed3f(fmaf(v, 0.2f, 0.5f), 0.0f, 1.0f);
}
// tanh = 1 - 2/(e^{2x}+1): exp overflow -> 1, exp(-inf) -> -1
__device__ __forceinline__ float tanh_fast(float x) {
    float e = __expf(2.0f * x);
    return 1.0f - __fdividef(2.0f, e + 1.0f);
}

// ---------------- MaxPool (1,2,2) -> bf16 ----------------
__global__ void pool_kernel(const float* __restrict__ in, u32* __restrict__ out) {
    int idx = blockIdx.x * 256 + threadIdx.x;
    const int total = B_ * T_ * HP * (WP / 2);
    if (idx >= total) return;
    int xp   = idx % (WP / 2);
    int rest = idx / (WP / 2);
    int y    = rest % HP;
    int bt   = rest / HP;
    const float* src = in + ((size_t)bt * HIN + 2 * y) * WIN + xp * 4;
    float4 a = *(const float4*)src;
    float4 b = *(const float4*)(src + WIN);
    float m0 = fmaxf(fmaxf(a.x, a.y), fmaxf(b.x, b.y));
    float m1 = fmaxf(fmaxf(a.z, a.w), fmaxf(b.z, b.w));
    out[((size_t)bt * HP + y) * (WP / 2) + xp] = (u32)f2bf(m0) | ((u32)f2bf(m1) << 16);
}

// ---------------- weight fragment pre-pack ----------------
// K layout: k = tap*16+ci (k<144 recurrent), k = 144+xtap (k<153 input conv), else 0.
// Frags 0..19: hi plane, f = q*4+nt. Frags 20..24: lo plane of nt=2 (z_c gate), f = 20+q.
// B-frag (16x16x32): lane l holds W[k = q*32 + (l>>4)*8 + j][n = nt*16 + (l&15)], j=0..7.
__global__ void frag_build(const float* __restrict__ krec, const float* __restrict__ kin,
                           int4* __restrict__ fragbuf) {
    int idx = blockIdx.x * 256 + threadIdx.x;
    if (idx >= NFRAG * 64) return;
    int l = idx & 63, f = idx >> 6;
    int lo = (f >= 20);
    int q  = lo ? (f - 20) : (f >> 2);
    int nt = lo ? 2 : (f & 3);
    int n = nt * 16 + (l & 15), o = l >> 4;
    u16 u[8];
    #pragma unroll
    for (int j = 0; j < 8; ++j) {
        int k = q * 32 + o * 8 + j;
        float wv = 0.0f;
        if (k < 144) wv = krec[k * 64 + n];
        else if (k < 153) wv = kin[(k - 144) * 64 + n];
        u16 hi = f2bf(wv);
        u[j] = lo ? f2bf(wv - bf2f(hi)) : hi;
    }
    int4 v;
    v.x = (int)((u32)u[0] | ((u32)u[1] << 16));
    v.y = (int)((u32)u[2] | ((u32)u[3] << 16));
    v.z = (int)((u32)u[4] | ((u32)u[5] << 16));
    v.w = (int)((u32)u[6] | ((u32)u[7] << 16));
    fragbuf[f * 64 + l] = v;
}

// ---------------- fused 2-step ConvLSTM ----------------
// Block: step-2 core = 4 rows x 62 cols at (y0, 62*bx). Step-1 computes h_t on the
// extended 6x64 strip (cols CB..CB+63, CB=62*bx-1) into LDS; c_t carried in regs.
// sh holds h_{t-1} (8x66, slot s <-> col CB-1+s), then aliased by h_t (6 rows,
// slot s <-> col CB-1+s with guard zeros at s=0,65). A-read col slot = wx+dx both steps.
__global__ __launch_bounds__(256, 4)
void lstm_fused(const u16* __restrict__ xpb, int t0,
                const u16* __restrict__ hin, u16* __restrict__ hout,
                const u16* __restrict__ cin, u16* __restrict__ cout,
                const int4* __restrict__ fragbuf,
                const float* __restrict__ bias) {
    __shared__ __align__(16) u16 sh[8 * 66 * PITCH];    // 25,344 B
    __shared__ __align__(16) u16 sxf[2 * NSLOT * 8];    // 12,288 B (total 37,632)

    const int tid = threadIdx.x;
    const int wv_ = tid >> 6;
    const int l   = tid & 63;
    const int o   = l >> 4;
    const int ci0 = (o & 1) * 8;
    const int wx  = wv_ * 16 + (l & 15);   // A-row (pixel) lane mapping
    const int ch  = l & 15;                // C-layout channel
    const int Lo0 = wv_ * 16 + o * 4;      // C-layout pixel base (+r)
    const int b   = blockIdx.z;
    const int y0  = blockIdx.y * TY;
    const int CB  = blockIdx.x * CPX - 1;
    const size_t hbB = (size_t)b * HO * WO * 16;

    // stage h_{t0-1}: rows y0-2..y0+5, cols CB-1..CB+64 (zeros at t0==0 / OOB)
    for (int i = tid; i < 8 * 66; i += 256) {
        int row = i / 66, s = i - row * 66;
        int gy = y0 - 2 + row, gx = CB - 1 + s;
        int4 v0 = make_int4(0, 0, 0, 0), v1 = v0;
        if (t0 > 0 && (u32)gy < (u32)HO && (u32)gx < (u32)WO) {
            const int4* g = (const int4*)&hin[hbB + ((size_t)gy * WO + gx) * 16];
            v0 = g[0]; v1 = g[1];
        }
        u16* d = &sh[i * PITCH];
        *(int4*)d = v0; *(int4*)(d + 8) = v1;
    }
    // pack x_{t0} A-frags: slot (R = 0..5, L = 0..63) -> output px (y0-1+R, CB+L)
    {
        const u16* xs = xpb + (size_t)(b * T_ + t0) * HP * WP;
        for (int slot = tid; slot < NSLOT; slot += 256) {
            int R = slot >> 6, L = slot & 63;
            int yy = y0 - 1 + R, gxb = CB + L;
            u16 u[9];
            #pragma unroll
            for (int j = 0; j < 9; ++j) {
                int gy = yy + j / 3, gx = gxb + j % 3;
                u[j] = ((u32)gy < (u32)HP && (u32)gx < (u32)WP) ? xs[(size_t)gy * WP + gx] : (u16)0;
            }
            int4 p;
            p.x = (int)((u32)u[0] | ((u32)u[1] << 16));
            p.y = (int)((u32)u[2] | ((u32)u[3] << 16));
            p.z = (int)((u32)u[4] | ((u32)u[5] << 16));
            p.w = (int)((u32)u[6] | ((u32)u[7] << 16));
            *(int4*)&sxf[slot * 8] = p;
            *(int4*)&sxf[(NSLOT + slot) * 8] = make_int4((int)(u32)u[8], 0, 0, 0);
        }
    }
    __syncthreads();

    float bv[4];
    #pragma unroll
    for (int nt = 0; nt < 4; ++nt) bv[nt] = bias[nt * 16 + ch];
    float c_keep[4][4];            // c_t for rows R=1..4 (step-2 rows m=R-1)
    const int4* fbl = fragbuf + l;

    // ================= STEP 1: h_t on 6x64 strip, two 3-row passes =================
    #pragma unroll
    for (int pass = 0; pass < 2; ++pass) {
        f32x4 acc[3][4];
        #pragma unroll
        for (int mm = 0; mm < 3; ++mm)
            #pragma unroll
            for (int nt = 0; nt < 4; ++nt)
                acc[mm][nt] = (f32x4){bv[nt], bv[nt], bv[nt], bv[nt]};

        if (t0 > 0) {
            #pragma unroll 1
            for (int q = 0; q < 4; ++q) {
                bf16x8 Bh0 = __builtin_bit_cast(bf16x8, fbl[(q * 4 + 0) * 64]);
                bf16x8 Bh1 = __builtin_bit_cast(bf16x8, fbl[(q * 4 + 1) * 64]);
                bf16x8 Bh2 = __builtin_bit_cast(bf16x8, fbl[(q * 4 + 2) * 64]);
                bf16x8 Bh3 = __builtin_bit_cast(bf16x8, fbl[(q * 4 + 3) * 64]);
                bf16x8 Bl2 = __builtin_bit_cast(bf16x8, fbl[(20 + q) * 64]);
                const int tap = 2 * q + (o >= 2 ? 1 : 0);
                const int dy = tap / 3, dx = tap - 3 * dy;
                #pragma unroll
                for (int mm = 0; mm < 3; ++mm) {
                    const int R = pass * 3 + mm;
                    bf16x8 Ah = *(const bf16x8*)&sh[((R + dy) * 66 + wx + dx) * PITCH + ci0];
                    acc[mm][0] = __builtin_amdgcn_mfma_f32_16x16x32_bf16(Ah, Bh0, acc[mm][0], 0, 0, 0);
                    acc[mm][1] = __builtin_amdgcn_mfma_f32_16x16x32_bf16(Ah, Bh1, acc[mm][1], 0, 0, 0);
                    acc[mm][2] = __builtin_amdgcn_mfma_f32_16x16x32_bf16(Ah, Bh2, acc[mm][2], 0, 0, 0);
                    acc[mm][2] = __builtin_amdgcn_mfma_f32_16x16x32_bf16(Ah, Bl2, acc[mm][2], 0, 0, 0);
                    acc[mm][3] = __builtin_amdgcn_mfma_f32_16x16x32_bf16(Ah, Bh3, acc[mm][3], 0, 0, 0);
                }
            }
        }
        // chunk 4: o<2 rec tap8 (staged zeros at t0==0); o==2 x taps 0..7; o==3 x tap8
        {
            bf16x8 Bh0 = __builtin_bit_cast(bf16x8, fbl[(16 + 0) * 64]);
            bf16x8 Bh1 = __builtin_bit_cast(bf16x8, fbl[(16 + 1) * 64]);
            bf16x8 Bh2 = __builtin_bit_cast(bf16x8, fbl[(16 + 2) * 64]);
            bf16x8 Bh3 = __builtin_bit_cast(bf16x8, fbl[(16 + 3) * 64]);
            bf16x8 Bl2 = __builtin_bit_cast(bf16x8, fbl[24 * 64]);
            #pragma unroll
            for (int mm = 0; mm < 3; ++mm) {
                const int R = pass * 3 + mm;
                bf16x8 Ah;
                if (o < 2)      Ah = *(const bf16x8*)&sh[((R + 2) * 66 + wx + 2) * PITCH + ci0];
                else if (o == 2) Ah = *(const bf16x8*)&sxf[(R * 64 + wx) * 8];
                else             Ah = *(const bf16x8*)&sxf[(NSLOT + R * 64 + wx) * 8];
                acc[mm][0] = __builtin_amdgcn_mfma_f32_16x16x32_bf16(Ah, Bh0, acc[mm][0], 0, 0, 0);
                acc[mm][1] = __builtin_amdgcn_mfma_f32_16x16x32_bf16(Ah, Bh1, acc[mm][1], 0, 0, 0);
                acc[mm][2] = __builtin_amdgcn_mfma_f32_16x16x32_bf16(Ah, Bh2, acc[mm][2], 0, 0, 0);
                acc[mm][2] = __builtin_amdgcn_mfma_f32_16x16x32_bf16(Ah, Bl2, acc[mm][2], 0, 0, 0);
                acc[mm][3] = __builtin_amdgcn_mfma_f32_16x16x32_bf16(Ah, Bh3, acc[mm][3], 0, 0, 0);
            }
        }
        __syncthreads();   // all waves done reading sh rows needed by this pass
        // epilogue: write h_t rows R into sh (aliasing prev rows R: disjoint from next
        // pass's reads rows 3..7). C layout: col=ch, row=(l>>4)*4+r.
        #pragma unroll
        for (int mm = 0; mm < 3; ++mm) {
            const int R = pass * 3 + mm;
            const int yy = y0 - 1 + R;
            #pragma unroll
            for (int r = 0; r < 4; ++r) {
                const int L = Lo0 + r;
                const int G = CB + L;
                const bool vp = ((u32)yy < (u32)HO) && ((u32)G < (u32)WO);
                float co = 0.0f;
                if (vp && t0 > 0) co = h2f(cin[hbB + ((size_t)yy * WO + G) * 16 + ch]);
                float zi = acc[mm][0][r], zf = acc[mm][1][r];
                float zc = acc[mm][2][r], zo = acc[mm][3][r];
                float cn = fmaf(hsg(zf), co, hsg(zi) * tanh_fast(zc));
                float hn = hsg(zo) * tanh_fast(cn);
                if (R >= 1 && R <= 4) c_keep[R - 1][r] = cn;
                sh[(R * 66 + L + 1) * PITCH + ch] = vp ? f2bf(hn) : (u16)0;
            }
        }
    }
    // guard cols (slots 0,65 of rows 0..5) + pack x_{t0+1} frags (256 slots)
    if (tid < 192) {
        int row = tid >> 5, side = (tid >> 4) & 1, cc = tid & 15;
        sh[(row * 66 + (side ? 65 : 0)) * PITCH + cc] = 0;
    }
    {
        const u16* xs = xpb + (size_t)(b * T_ + t0 + 1) * HP * WP;
        int m = tid >> 6, L = tid & 63;
        int yy = y0 + m, gxb = CB + L;
        u16 u[9];
        #pragma unroll
        for (int j = 0; j < 9; ++j) {
            int gy = yy + j / 3, gx = gxb + j % 3;
            u[j] = ((u32)gy < (u32)HP && (u32)gx < (u32)WP) ? xs[(size_t)gy * WP + gx] : (u16)0;
        }
        int4 p;
        p.x = (int)((u32)u[0] | ((u32)u[1] << 16));
        p.y = (int)((u32)u[2] | ((u32)u[3] << 16));
        p.z = (int)((u32)u[4] | ((u32)u[5] << 16));
        p.w = (int)((u32)u[6] | ((u32)u[7] << 16));
        *(int4*)&sxf[tid * 8] = p;
        *(int4*)&sxf[(NSLOT + tid) * 8] = make_int4((int)(u32)u[8], 0, 0, 0);
    }
    __syncthreads();

    // ================= STEP 2: h_{t0+1}, c_{t0+1} on 4x62 core =================
    {
        f32x4 acc[4][4];
        #pragma unroll
        for (int m = 0; m < 4; ++m)
            #pragma unroll
            for (int nt = 0; nt < 4; ++nt)
                acc[m][nt] = (f32x4){bv[nt], bv[nt], bv[nt], bv[nt]};

        #pragma unroll 1
        for (int q = 0; q < 4; ++q) {
            bf16x8 Bh0 = __builtin_bit_cast(bf16x8, fbl[(q * 4 + 0) * 64]);
            bf16x8 Bh1 = __builtin_bit_cast(bf16x8, fbl[(q * 4 + 1) * 64]);
            bf16x8 Bh2 = __builtin_bit_cast(bf16x8, fbl[(q * 4 + 2) * 64]);
            bf16x8 Bh3 = __builtin_bit_cast(bf16x8, fbl[(q * 4 + 3) * 64]);
            bf16x8 Bl2 = __builtin_bit_cast(bf16x8, fbl[(20 + q) * 64]);
            const int tap = 2 * q + (o >= 2 ? 1 : 0);
            const int dy = tap / 3, dx = tap - 3 * dy;
            #pragma unroll
            for (int m = 0; m < 4; ++m) {
                bf16x8 Ah = *(const bf16x8*)&sh[((m + dy) * 66 + wx + dx) * PITCH + ci0];
                acc[m][0] = __builtin_amdgcn_mfma_f32_16x16x32_bf16(Ah, Bh0, acc[m][0], 0, 0, 0);
                acc[m][1] = __builtin_amdgcn_mfma_f32_16x16x32_bf16(Ah, Bh1, acc[m][1], 0, 0, 0);
                acc[m][2] = __builtin_amdgcn_mfma_f32_16x16x32_bf16(Ah, Bh2, acc[m][2], 0, 0, 0);
                acc[m][2] = __builtin_amdgcn_mfma_f32_16x16x32_bf16(Ah, Bl2, acc[m][2], 0, 0, 0);
                acc[m][3] = __builtin_amdgcn_mfma_f32_16x16x32_bf16(Ah, Bh3, acc[m][3], 0, 0, 0);
            }
        }
        {
            bf16x8 Bh0 = __builtin_bit_cast(bf16x8, fbl[(16 + 0) * 64]);
            bf16x8 Bh1 = __builtin_bit_cast(bf16x8, fbl[(16 + 1) * 64]);
            bf16x8 Bh2 = __builtin_bit_cast(bf16x8, fbl[(16 + 2) * 64]);
            bf16x8 Bh3 = __builtin_bit_cast(bf16x8, fbl[(16 + 3) * 64]);
            bf16x8 Bl2 = __builtin_bit_cast(bf16x8, fbl[24 * 64]);
            #pragma unroll
            for (int m = 0; m < 4; ++m) {
                bf16x8 Ah;
                if (o < 2)      Ah = *(const bf16x8*)&sh[((m + 2) * 66 + wx + 2) * PITCH + ci0];
                else if (o == 2) Ah = *(const bf16x8*)&sxf[(m * 64 + wx) * 8];
                else             Ah = *(const bf16x8*)&sxf[(NSLOT + m * 64 + wx) * 8];
                acc[m][0] = __builtin_amdgcn_mfma_f32_16x16x32_bf16(Ah, Bh0, acc[m][0], 0, 0, 0);
                acc[m][1] = __builtin_amdgcn_mfma_f32_16x16x32_bf16(Ah, Bh1, acc[m][1], 0, 0, 0);
                acc[m][2] = __builtin_amdgcn_mfma_f32_16x16x32_bf16(Ah, Bh2, acc[m][2], 0, 0, 0);
                acc[m][2] = __builtin_amdgcn_mfma_f32_16x16x32_bf16(Ah, Bl2, acc[m][2], 0, 0, 0);
                acc[m][3] = __builtin_amdgcn_mfma_f32_16x16x32_bf16(Ah, Bh3, acc[m][3], 0, 0, 0);
            }
        }
        // epilogue: core only (L in 1..62, real pixels)
        #pragma unroll
        for (int m = 0; m < 4; ++m) {
            const int yy = y0 + m;
            #pragma unroll
            for (int r = 0; r < 4; ++r) {
                const int L = Lo0 + r;
                const int G = CB + L;
                if ((u32)yy < (u32)HO && L >= 1 && L <= CPX && G < WO) {
                    float co = c_keep[m][r];
                    float zi = acc[m][0][r], zf = acc[m][1][r];
                    float zc = acc[m][2][r], zo = acc[m][3][r];
                    float cn = fmaf(hsg(zf), co, hsg(zi) * tanh_fast(zc));
                    float hn = hsg(zo) * tanh_fast(cn);
                    size_t gc = hbB + ((size_t)yy * WO + G) * 16 + ch;
                    cout[gc] = f2h(cn);
                    hout[gc] = f2bf(hn);
                }
            }
        }
    }
}

// ---------------- dense ----------------
#define NPX    (HO * WO)                       // 75,684 pixels
#define PCHUNK 512
#define NCHUNK ((NPX + PCHUNK - 1) / PCHUNK)   // 148

__device__ __forceinline__ float dot2(u32 a, float w0, float w1, float s) {
    s = fmaf(bf2f((u16)a), w0, s);
    return fmaf(bf2f((u16)(a >> 16)), w1, s);
}

__global__ void dense1(const u16* __restrict__ h, const float* __restrict__ w,
                       float* __restrict__ partial) {
    int b = blockIdx.y, tid = threadIdx.x;
    const u16* hb = h + (size_t)b * NPX * 16;
    float s = 0.0f;
    #pragma unroll
    for (int pp = 0; pp < 2; ++pp) {
        int px = blockIdx.x * PCHUNK + tid * 2 + pp;
        if (px < NPX) {
            const int4* g = (const int4*)&hb[(size_t)px * 16];
            int4 a0 = g[0], a1 = g[1];
            const float* wp = &w[(size_t)px * 16];
            s = dot2((u32)a0.x, wp[0],  wp[1],  s);
            s = dot2((u32)a0.y, wp[2],  wp[3],  s);
            s = dot2((u32)a0.z, wp[4],  wp[5],  s);
            s = dot2((u32)a0.w, wp[6],  wp[7],  s);
            s = dot2((u32)a1.x, wp[8],  wp[9],  s);
            s = dot2((u32)a1.y, wp[10], wp[11], s);
            s = dot2((u32)a1.z, wp[12], wp[13], s);
            s = dot2((u32)a1.w, wp[14], wp[15], s);
        }
    }
    #pragma unroll
    for (int of = 32; of > 0; of >>= 1) s += __shfl_down(s, of, 64);
    __shared__ float red[4];
    if ((tid & 63) == 0) red[tid >> 6] = s;
    __syncthreads();
    if (tid == 0) partial[b * NCHUNK + blockIdx.x] = red[0] + red[1] + red[2] + red[3];
}

__global__ void dense2(const float* __restrict__ partial, const float* __restrict__ db,
                       float* __restrict__ out) {
    int b = blockIdx.x, tid = threadIdx.x;
    float s = 0.0f;
    for (int i = tid; i < NCHUNK; i += 256) s += partial[b * NCHUNK + i];
    #pragma unroll
    for (int of = 32; of > 0; of >>= 1) s += __shfl_down(s, of, 64);
    __shared__ float red[4];
    if ((tid & 63) == 0) red[tid >> 6] = s;
    __syncthreads();
    if (tid == 0) out[b] = red[0] + red[1] + red[2] + red[3] + db[0];
}

extern "C" void kernel_launch(void* const* d_in, const int* in_sizes, int n_in,
                              void* d_out, int out_size, void* d_ws, size_t ws_size,
                              hipStream_t stream) {
    const float* inputs = (const float*)d_in[0];
    const float* kin    = (const float*)d_in[1];
    const float* krec   = (const float*)d_in[2];
    const float* bias   = (const float*)d_in[3];
    const float* dw     = (const float*)d_in[4];
    const float* db     = (const float*)d_in[5];
    float* out = (float*)d_out;

    const size_t XPN = (size_t)B_ * T_ * HP * WP;   // 9,830,400 u16 (bf16 pooled x)
    const size_t HN  = (size_t)B_ * HO * WO * 16;   // 9,687,552 u16 per state buffer

    u16*   xp   = (u16*)d_ws;
    u16*   hA   = xp + XPN;
    u16*   hB   = hA + HN;
    u16*   cA   = hB + HN;                          // fp16 c buffers
    u16*   cB   = cA + HN;
    int4*  frag = (int4*)(cB + HN);                 // 25,600 B
    float* part = (float*)(frag + NFRAG * 64);

    {
        int total = B_ * T_ * HP * (WP / 2);
        pool_kernel<<<(total + 255) / 256, 256, 0, stream>>>(inputs, (u32*)xp);
    }
    frag_build<<<(NFRAG * 64 + 255) / 256, 256, 0, stream>>>(krec, kin, frag);

    u16* hb[2] = {hA, hB};
    u16* cb[2] = {cA, cB};
    dim3 grid(4, (HO + TY - 1) / TY, B_);   // 4 x 80 x 8
    for (int s = 0; s < 8; ++s) {
        lstm_fused<<<grid, 256, 0, stream>>>(xp, 2 * s,
                                             hb[(s + 1) & 1], hb[s & 1],
                                             cb[(s + 1) & 1], cb[s & 1],
                                             frag, bias);
    }
    // s=7 wrote hb[1]
    dense1<<<dim3(NCHUNK, B_), 256, 0, stream>>>(hb[1], dw, part);
    dense2<<<B_, 256, 0, stream>>>(part, db, out);
}

// Round 11
// 861.871 us; speedup vs baseline: 1.3610x; 1.3610x over previous
//
#include <hip/hip_runtime.h>
#include <hip/hip_bf16.h>
#include <cstdint>

#define B_  8
#define T_  16
#define HIN 640
#define WIN 480
#define HP  320
#define WP  240
#define HO  318
#define WO  238

typedef unsigned short u16;
typedef unsigned int   u32;
typedef __attribute__((ext_vector_type(8))) short bf16x8;
typedef __attribute__((ext_vector_type(4))) float f32x4;

#define TY    4
#define PITCH 24    // halfwords per pixel slot (48 B): b128-aligned, ~2-way banks
#define NFRAG 25    // 20 hi (q0..4 x nt0..3) + 5 lo (nt=2 only, q0..4)
#define NSLOT 384   // x A-frag slots (6 rows x 64 cols) for step-1
#define CPX   62    // core output cols per x-tile (step-2)

__device__ __forceinline__ u16 f2bf(float f) {          // RNE float->bf16 bits
    u32 u = __float_as_uint(f);
    return (u16)((u + 0x7fffu + ((u >> 16) & 1u)) >> 16);
}
__device__ __forceinline__ float bf2f(u16 u) {
    return __uint_as_float(((u32)u) << 16);
}
__device__ __forceinline__ float h2f(u16 u) {           // fp16 bits -> f32
    _Float16 h = __builtin_bit_cast(_Float16, u);
    return (float)h;
}
__device__ __forceinline__ u16 f2h(float f) {           // f32 -> fp16 bits
    _Float16 h = (_Float16)f;
    return __builtin_bit_cast(u16, h);
}
__device__ __forceinline__ float hsg(float v) {         // med3 clamp
    return __builtin_amdgcn_fmed3f(fmaf(v, 0.2f, 0.5f), 0.0f, 1.0f);
}
// tanh = 1 - 2/(e^{2x}+1): exp overflow -> 1, exp(-inf) -> -1
__device__ __forceinline__ float tanh_fast(float x) {
    float e = __expf(2.0f * x);
    return 1.0f - __fdividef(2.0f, e + 1.0f);
}

// ---------------- MaxPool (1,2,2) -> bf16 ----------------
__global__ void pool_kernel(const float* __restrict__ in, u32* __restrict__ out) {
    int idx = blockIdx.x * 256 + threadIdx.x;
    const int total = B_ * T_ * HP * (WP / 2);
    if (idx >= total) return;
    int xp   = idx % (WP / 2);
    int rest = idx / (WP / 2);
    int y    = rest % HP;
    int bt   = rest / HP;
    const float* src = in + ((size_t)bt * HIN + 2 * y) * WIN + xp * 4;
    float4 a = *(const float4*)src;
    float4 b = *(const float4*)(src + WIN);
    float m0 = fmaxf(fmaxf(a.x, a.y), fmaxf(b.x, b.y));
    float m1 = fmaxf(fmaxf(a.z, a.w), fmaxf(b.z, b.w));
    out[((size_t)bt * HP + y) * (WP / 2) + xp] = (u32)f2bf(m0) | ((u32)f2bf(m1) << 16);
}

// ---------------- weight fragment pre-pack ----------------
// K layout: k = tap*16+ci (k<144 recurrent), k = 144+xtap (k<153 input conv), else 0.
// Frags 0..19: hi plane, f = q*4+nt. Frags 20..24: lo plane of nt=2 (z_c gate), f = 20+q.
// B-frag (16x16x32): lane l holds W[k = q*32 + (l>>4)*8 + j][n = nt*16 + (l&15)], j=0..7.
__global__ void frag_build(const float* __restrict__ krec, const float* __restrict__ kin,
                           int4* __restrict__ fragbuf) {
    int idx = blockIdx.x * 256 + threadIdx.x;
    if (idx >= NFRAG * 64) return;
    int l = idx & 63, f = idx >> 6;
    int lo = (f >= 20);
    int q  = lo ? (f - 20) : (f >> 2);
    int nt = lo ? 2 : (f & 3);
    int n = nt * 16 + (l & 15), o = l >> 4;
    u16 u[8];
    #pragma unroll
    for (int j = 0; j < 8; ++j) {
        int k = q * 32 + o * 8 + j;
        float wv = 0.0f;
        if (k < 144) wv = krec[k * 64 + n];
        else if (k < 153) wv = kin[(k - 144) * 64 + n];
        u16 hi = f2bf(wv);
        u[j] = lo ? f2bf(wv - bf2f(hi)) : hi;
    }
    int4 v;
    v.x = (int)((u32)u[0] | ((u32)u[1] << 16));
    v.y = (int)((u32)u[2] | ((u32)u[3] << 16));
    v.z = (int)((u32)u[4] | ((u32)u[5] << 16));
    v.w = (int)((u32)u[6] | ((u32)u[7] << 16));
    fragbuf[f * 64 + l] = v;
}

struct Acc4 { f32x4 v[2][4]; };

// ---------------- fused 2-step ConvLSTM (2-row passes, no spill) ----------------
// Step-2 core = 4 rows x 62 cols at (y0, 62*bx). Step-1 computes h_t on the 6x64
// extended strip (cols CB..CB+63, CB=62*bx-1) into LDS; c_t core rows in regs.
// sh: h_{t-1} rows 0..7 (gy = y0-2+row), aliased by h_t strip rows 0..5 post-pass.
__global__ __launch_bounds__(256, 4)
void lstm_fused(const u16* __restrict__ xpb, int t0,
                const u16* __restrict__ hin, u16* __restrict__ hout,
                const u16* __restrict__ cin, u16* __restrict__ cout,
                const int4* __restrict__ fragbuf,
                const float* __restrict__ bias) {
    __shared__ __align__(16) u16 sh[8 * 66 * PITCH];    // 25,344 B
    __shared__ __align__(16) u16 sxf[2 * NSLOT * 8];    // 12,288 B (total 37,632)

    const int tid = threadIdx.x;
    const int wv_ = tid >> 6;
    const int l   = tid & 63;
    const int o   = l >> 4;
    const int ci0 = (o & 1) * 8;
    const int wx  = wv_ * 16 + (l & 15);   // A-row (pixel) lane mapping
    const int ch  = l & 15;                // C-layout channel
    const int Lo0 = wv_ * 16 + o * 4;      // C-layout pixel base (+r)
    const int b   = blockIdx.z;
    const int y0  = blockIdx.y * TY;
    const int CB  = blockIdx.x * CPX - 1;
    const size_t hbB = (size_t)b * HO * WO * 16;

    // stage h_{t0-1}: rows y0-2..y0+5, cols CB-1..CB+64 (zeros at t0==0 / OOB)
    for (int i = tid; i < 8 * 66; i += 256) {
        int row = i / 66, s = i - row * 66;
        int gy = y0 - 2 + row, gx = CB - 1 + s;
        int4 v0 = make_int4(0, 0, 0, 0), v1 = v0;
        if (t0 > 0 && (u32)gy < (u32)HO && (u32)gx < (u32)WO) {
            const int4* g = (const int4*)&hin[hbB + ((size_t)gy * WO + gx) * 16];
            v0 = g[0]; v1 = g[1];
        }
        u16* d = &sh[i * PITCH];
        *(int4*)d = v0; *(int4*)(d + 8) = v1;
    }
    // pack x_{t0} A-frags: slot (R = 0..5, L = 0..63) -> strip px (y0-1+R, CB+L)
    {
        const u16* xs = xpb + (size_t)(b * T_ + t0) * HP * WP;
        for (int slot = tid; slot < NSLOT; slot += 256) {
            int R = slot >> 6, L = slot & 63;
            int yy = y0 - 1 + R, gxb = CB + L;
            u16 u[9];
            #pragma unroll
            for (int j = 0; j < 9; ++j) {
                int gy = yy + j / 3, gx = gxb + j % 3;
                u[j] = ((u32)gy < (u32)HP && (u32)gx < (u32)WP) ? xs[(size_t)gy * WP + gx] : (u16)0;
            }
            int4 p;
            p.x = (int)((u32)u[0] | ((u32)u[1] << 16));
            p.y = (int)((u32)u[2] | ((u32)u[3] << 16));
            p.z = (int)((u32)u[4] | ((u32)u[5] << 16));
            p.w = (int)((u32)u[6] | ((u32)u[7] << 16));
            *(int4*)&sxf[slot * 8] = p;
            *(int4*)&sxf[(NSLOT + slot) * 8] = make_int4((int)(u32)u[8], 0, 0, 0);
        }
    }
    __syncthreads();

    float bv[4];
    #pragma unroll
    for (int nt = 0; nt < 4; ++nt) bv[nt] = bias[nt * 16 + ch];
    float c_keep[4][4];            // c_t for strip rows R=1..4 (step-2 rows m=R-1)
    const int4* fbl = fragbuf + l;

    // 2-row MFMA: rows RB, RB+1. Same index algebra serves step-1 (h_{t-1} in sh)
    // and step-2 (h_t in sh rows 0..5, fresh x frags in sxf slots 0..255).
    auto mfma_rows = [&](int RB, bool dorec) {
        Acc4 A4;
        #pragma unroll
        for (int mm = 0; mm < 2; ++mm)
            #pragma unroll
            for (int nt = 0; nt < 4; ++nt)
                A4.v[mm][nt] = (f32x4){bv[nt], bv[nt], bv[nt], bv[nt]};
        if (dorec) {
            #pragma unroll 1
            for (int q = 0; q < 4; ++q) {
                bf16x8 Bh0 = __builtin_bit_cast(bf16x8, fbl[(q * 4 + 0) * 64]);
                bf16x8 Bh1 = __builtin_bit_cast(bf16x8, fbl[(q * 4 + 1) * 64]);
                bf16x8 Bh2 = __builtin_bit_cast(bf16x8, fbl[(q * 4 + 2) * 64]);
                bf16x8 Bh3 = __builtin_bit_cast(bf16x8, fbl[(q * 4 + 3) * 64]);
                bf16x8 Bl2 = __builtin_bit_cast(bf16x8, fbl[(20 + q) * 64]);
                const int tap = 2 * q + (o >= 2 ? 1 : 0);
                const int dy = tap / 3, dx = tap - 3 * dy;
                #pragma unroll
                for (int mm = 0; mm < 2; ++mm) {
                    bf16x8 Ah = *(const bf16x8*)&sh[((RB + mm + dy) * 66 + wx + dx) * PITCH + ci0];
                    A4.v[mm][0] = __builtin_amdgcn_mfma_f32_16x16x32_bf16(Ah, Bh0, A4.v[mm][0], 0, 0, 0);
                    A4.v[mm][1] = __builtin_amdgcn_mfma_f32_16x16x32_bf16(Ah, Bh1, A4.v[mm][1], 0, 0, 0);
                    A4.v[mm][2] = __builtin_amdgcn_mfma_f32_16x16x32_bf16(Ah, Bh2, A4.v[mm][2], 0, 0, 0);
                    A4.v[mm][2] = __builtin_amdgcn_mfma_f32_16x16x32_bf16(Ah, Bl2, A4.v[mm][2], 0, 0, 0);
                    A4.v[mm][3] = __builtin_amdgcn_mfma_f32_16x16x32_bf16(Ah, Bh3, A4.v[mm][3], 0, 0, 0);
                }
            }
        }
        {   // chunk 4: o<2 rec tap8; o==2 x taps 0..7; o==3 x tap8 + zero-weights
            bf16x8 Bh0 = __builtin_bit_cast(bf16x8, fbl[(16 + 0) * 64]);
            bf16x8 Bh1 = __builtin_bit_cast(bf16x8, fbl[(16 + 1) * 64]);
            bf16x8 Bh2 = __builtin_bit_cast(bf16x8, fbl[(16 + 2) * 64]);
            bf16x8 Bh3 = __builtin_bit_cast(bf16x8, fbl[(16 + 3) * 64]);
            bf16x8 Bl2 = __builtin_bit_cast(bf16x8, fbl[24 * 64]);
            #pragma unroll
            for (int mm = 0; mm < 2; ++mm) {
                const int R = RB + mm;
                bf16x8 Ah;
                if (o < 2)       Ah = *(const bf16x8*)&sh[((R + 2) * 66 + wx + 2) * PITCH + ci0];
                else if (o == 2) Ah = *(const bf16x8*)&sxf[(R * 64 + wx) * 8];
                else             Ah = *(const bf16x8*)&sxf[(NSLOT + R * 64 + wx) * 8];
                A4.v[mm][0] = __builtin_amdgcn_mfma_f32_16x16x32_bf16(Ah, Bh0, A4.v[mm][0], 0, 0, 0);
                A4.v[mm][1] = __builtin_amdgcn_mfma_f32_16x16x32_bf16(Ah, Bh1, A4.v[mm][1], 0, 0, 0);
                A4.v[mm][2] = __builtin_amdgcn_mfma_f32_16x16x32_bf16(Ah, Bh2, A4.v[mm][2], 0, 0, 0);
                A4.v[mm][2] = __builtin_amdgcn_mfma_f32_16x16x32_bf16(Ah, Bl2, A4.v[mm][2], 0, 0, 0);
                A4.v[mm][3] = __builtin_amdgcn_mfma_f32_16x16x32_bf16(Ah, Bh3, A4.v[mm][3], 0, 0, 0);
            }
        }
        return A4;
    };

// step-1 epilogue row: c from global, h_t -> LDS, optional c_keep (compile-time)
#define EPI1(AV, R, KEEP) { \
    const int yy = y0 - 1 + (R); \
    _Pragma("unroll") \
    for (int r = 0; r < 4; ++r) { \
        const int L = Lo0 + r, G = CB + L; \
        const bool vp = ((u32)yy < (u32)HO) && ((u32)G < (u32)WO); \
        float co = 0.0f; \
        if (vp && t0 > 0) co = h2f(cin[hbB + ((size_t)yy * WO + G) * 16 + ch]); \
        float zi = AV[0][r], zf = AV[1][r], zc = AV[2][r], zo = AV[3][r]; \
        float cn = fmaf(hsg(zf), co, hsg(zi) * tanh_fast(zc)); \
        float hn = hsg(zo) * tanh_fast(cn); \
        KEEP; \
        sh[((R) * 66 + L + 1) * PITCH + ch] = vp ? f2bf(hn) : (u16)0; \
    } }

    // ===== STEP 1: three 2-row passes (reads sh rows RB..RB+3; writes RB..RB+1) =====
    {
        Acc4 a0 = mfma_rows(0, t0 > 0);
        __syncthreads();
        EPI1(a0.v[0], 0, (void)cn);
        EPI1(a0.v[1], 1, c_keep[0][r] = cn);
    }
    {
        Acc4 a1 = mfma_rows(2, t0 > 0);
        __syncthreads();
        EPI1(a1.v[0], 2, c_keep[1][r] = cn);
        EPI1(a1.v[1], 3, c_keep[2][r] = cn);
    }
    {
        Acc4 a2 = mfma_rows(4, t0 > 0);
        __syncthreads();
        EPI1(a2.v[0], 4, c_keep[3][r] = cn);
        EPI1(a2.v[1], 5, (void)cn);
    }

    // guard cols (slots 0,65 of rows 0..5) + pack x_{t0+1} frags (slots 0..255)
    if (tid < 192) {
        int row = tid >> 5, side = (tid >> 4) & 1, cc = tid & 15;
        sh[(row * 66 + (side ? 65 : 0)) * PITCH + cc] = 0;
    }
    {
        const u16* xs = xpb + (size_t)(b * T_ + t0 + 1) * HP * WP;
        int m = tid >> 6, L = tid & 63;
        int yy = y0 + m, gxb = CB + L;
        u16 u[9];
        #pragma unroll
        for (int j = 0; j < 9; ++j) {
            int gy = yy + j / 3, gx = gxb + j % 3;
            u[j] = ((u32)gy < (u32)HP && (u32)gx < (u32)WP) ? xs[(size_t)gy * WP + gx] : (u16)0;
        }
        int4 p;
        p.x = (int)((u32)u[0] | ((u32)u[1] << 16));
        p.y = (int)((u32)u[2] | ((u32)u[3] << 16));
        p.z = (int)((u32)u[4] | ((u32)u[5] << 16));
        p.w = (int)((u32)u[6] | ((u32)u[7] << 16));
        *(int4*)&sxf[tid * 8] = p;
        *(int4*)&sxf[(NSLOT + tid) * 8] = make_int4((int)(u32)u[8], 0, 0, 0);
    }
    __syncthreads();

// step-2 epilogue row: core-only, c from regs, h/c -> global
#define EPI2(AV, M, CK) { \
    const int yy = y0 + (M); \
    _Pragma("unroll") \
    for (int r = 0; r < 4; ++r) { \
        const int L = Lo0 + r, G = CB + L; \
        if ((u32)yy < (u32)HO && L >= 1 && L <= CPX && G < WO) { \
            float co = CK[r]; \
            float zi = AV[0][r], zf = AV[1][r], zc = AV[2][r], zo = AV[3][r]; \
            float cn = fmaf(hsg(zf), co, hsg(zi) * tanh_fast(zc)); \
            float hn = hsg(zo) * tanh_fast(cn); \
            size_t gc = hbB + ((size_t)yy * WO + G) * 16 + ch; \
            cout[gc] = f2h(cn); \
            hout[gc] = f2bf(hn); \
        } \
    } }

    // ===== STEP 2: two 2-row passes (read-only LDS; no syncs needed between) =====
    {
        Acc4 a0 = mfma_rows(0, true);
        EPI2(a0.v[0], 0, c_keep[0]);
        EPI2(a0.v[1], 1, c_keep[1]);
    }
    {
        Acc4 a1 = mfma_rows(2, true);
        EPI2(a1.v[0], 2, c_keep[2]);
        EPI2(a1.v[1], 3, c_keep[3]);
    }
#undef EPI1
#undef EPI2
}

// ---------------- dense ----------------
#define NPX    (HO * WO)                       // 75,684 pixels
#define PCHUNK 512
#define NCHUNK ((NPX + PCHUNK - 1) / PCHUNK)   // 148

__device__ __forceinline__ float dot2(u32 a, float w0, float w1, float s) {
    s = fmaf(bf2f((u16)a), w0, s);
    return fmaf(bf2f((u16)(a >> 16)), w1, s);
}

__global__ void dense1(const u16* __restrict__ h, const float* __restrict__ w,
                       float* __restrict__ partial) {
    int b = blockIdx.y, tid = threadIdx.x;
    const u16* hb = h + (size_t)b * NPX * 16;
    float s = 0.0f;
    #pragma unroll
    for (int pp = 0; pp < 2; ++pp) {
        int px = blockIdx.x * PCHUNK + tid * 2 + pp;
        if (px < NPX) {
            const int4* g = (const int4*)&hb[(size_t)px * 16];
            int4 a0 = g[0], a1 = g[1];
            const float* wp = &w[(size_t)px * 16];
            s = dot2((u32)a0.x, wp[0],  wp[1],  s);
            s = dot2((u32)a0.y, wp[2],  wp[3],  s);
            s = dot2((u32)a0.z, wp[4],  wp[5],  s);
            s = dot2((u32)a0.w, wp[6],  wp[7],  s);
            s = dot2((u32)a1.x, wp[8],  wp[9],  s);
            s = dot2((u32)a1.y, wp[10], wp[11], s);
            s = dot2((u32)a1.z, wp[12], wp[13], s);
            s = dot2((u32)a1.w, wp[14], wp[15], s);
        }
    }
    #pragma unroll
    for (int of = 32; of > 0; of >>= 1) s += __shfl_down(s, of, 64);
    __shared__ float red[4];
    if ((tid & 63) == 0) red[tid >> 6] = s;
    __syncthreads();
    if (tid == 0) partial[b * NCHUNK + blockIdx.x] = red[0] + red[1] + red[2] + red[3];
}

__global__ void dense2(const float* __restrict__ partial, const float* __restrict__ db,
                       float* __restrict__ out) {
    int b = blockIdx.x, tid = threadIdx.x;
    float s = 0.0f;
    for (int i = tid; i < NCHUNK; i += 256) s += partial[b * NCHUNK + i];
    #pragma unroll
    for (int of = 32; of > 0; of >>= 1) s += __shfl_down(s, of, 64);
    __shared__ float red[4];
    if ((tid & 63) == 0) red[tid >> 6] = s;
    __syncthreads();
    if (tid == 0) out[b] = red[0] + red[1] + red[2] + red[3] + db[0];
}

extern "C" void kernel_launch(void* const* d_in, const int* in_sizes, int n_in,
                              void* d_out, int out_size, void* d_ws, size_t ws_size,
                              hipStream_t stream) {
    const float* inputs = (const float*)d_in[0];
    const float* kin    = (const float*)d_in[1];
    const float* krec   = (const float*)d_in[2];
    const float* bias   = (const float*)d_in[3];
    const float* dw     = (const float*)d_in[4];
    const float* db     = (const float*)d_in[5];
    float* out = (float*)d_out;

    const size_t XPN = (size_t)B_ * T_ * HP * WP;   // 9,830,400 u16 (bf16 pooled x)
    const size_t HN  = (size_t)B_ * HO * WO * 16;   // 9,687,552 u16 per state buffer

    u16*   xp   = (u16*)d_ws;
    u16*   hA   = xp + XPN;
    u16*   hB   = hA + HN;
    u16*   cA   = hB + HN;                          // fp16 c buffers
    u16*   cB   = cA + HN;
    int4*  frag = (int4*)(cB + HN);                 // 25,600 B
    float* part = (float*)(frag + NFRAG * 64);

    {
        int total = B_ * T_ * HP * (WP / 2);
        pool_kernel<<<(total + 255) / 256, 256, 0, stream>>>(inputs, (u32*)xp);
    }
    frag_build<<<(NFRAG * 64 + 255) / 256, 256, 0, stream>>>(krec, kin, frag);

    u16* hb[2] = {hA, hB};
    u16* cb[2] = {cA, cB};
    dim3 grid(4, (HO + TY - 1) / TY, B_);   // 4 x 80 x 8
    for (int s = 0; s < 8; ++s) {
        lstm_fused<<<grid, 256, 0, stream>>>(xp, 2 * s,
                                             hb[(s + 1) & 1], hb[s & 1],
                                             cb[(s + 1) & 1], cb[s & 1],
                                             frag, bias);
    }
    // s=7 wrote hb[1]
    dense1<<<dim3(NCHUNK, B_), 256, 0, stream>>>(hb[1], dw, part);
    dense2<<<B_, 256, 0, stream>>>(part, db, out);
}

// Round 12
// 663.594 us; speedup vs baseline: 1.7677x; 1.2988x over previous
//
#include <hip/hip_runtime.h>
#include <hip/hip_bf16.h>
#include <cstdint>

#define B_  8
#define T_  16
#define HIN 640
#define WIN 480
#define HP  320
#define WP  240
#define HO  318
#define WO  238

typedef unsigned short u16;
typedef unsigned int   u32;
typedef __attribute__((ext_vector_type(8))) short bf16x8;
typedef __attribute__((ext_vector_type(4))) float f32x4;

#define TY    4
#define PITCH 24   // halfwords per pixel slot (48 B): b128-aligned, ~2-way banks
#define NFRAG 25   // 20 hi (q0..4 x nt0..3) + 5 lo (nt=2 only, q0..4)

__device__ __forceinline__ u16 f2bf(float f) {          // RNE float->bf16 bits
    u32 u = __float_as_uint(f);
    return (u16)((u + 0x7fffu + ((u >> 16) & 1u)) >> 16);
}
__device__ __forceinline__ float bf2f(u16 u) {
    return __uint_as_float(((u32)u) << 16);
}
__device__ __forceinline__ float h2f(u16 u) {           // fp16 bits -> f32
    _Float16 h = __builtin_bit_cast(_Float16, u);
    return (float)h;
}
__device__ __forceinline__ u16 f2h(float f) {           // f32 -> fp16 bits
    _Float16 h = (_Float16)f;
    return __builtin_bit_cast(u16, h);
}
__device__ __forceinline__ float hsg(float v) {         // med3 clamp
    return __builtin_amdgcn_fmed3f(fmaf(v, 0.2f, 0.5f), 0.0f, 1.0f);
}
// tanh = 1 - 2/(e^{2x}+1): exp overflow -> 1, exp(-inf) -> -1
__device__ __forceinline__ float tanh_fast(float x) {
    float e = __expf(2.0f * x);
    return 1.0f - __fdividef(2.0f, e + 1.0f);
}

// ---------------- MaxPool (1,2,2) -> bf16 ----------------
__global__ void pool_kernel(const float* __restrict__ in, u32* __restrict__ out) {
    int idx = blockIdx.x * 256 + threadIdx.x;
    const int total = B_ * T_ * HP * (WP / 2);
    if (idx >= total) return;
    int xp   = idx % (WP / 2);
    int rest = idx / (WP / 2);
    int y    = rest % HP;
    int bt   = rest / HP;
    const float* src = in + ((size_t)bt * HIN + 2 * y) * WIN + xp * 4;
    float4 a = *(const float4*)src;
    float4 b = *(const float4*)(src + WIN);
    float m0 = fmaxf(fmaxf(a.x, a.y), fmaxf(b.x, b.y));
    float m1 = fmaxf(fmaxf(a.z, a.w), fmaxf(b.z, b.w));
    out[((size_t)bt * HP + y) * (WP / 2) + xp] = (u32)f2bf(m0) | ((u32)f2bf(m1) << 16);
}

// ---------------- weight fragment pre-pack ----------------
// K layout: k = tap*16+ci (k<144 recurrent), k = 144+xtap (k<153 input conv), else 0.
// Frags 0..19: hi plane, f = q*4+nt. Frags 20..24: lo plane of nt=2 (z_c gate), f = 20+q.
// B-frag (16x16x32): lane l holds W[k = q*32 + (l>>4)*8 + j][n = nt*16 + (l&15)], j=0..7.
__global__ void frag_build(const float* __restrict__ krec, const float* __restrict__ kin,
                           int4* __restrict__ fragbuf) {
    int idx = blockIdx.x * 256 + threadIdx.x;
    if (idx >= NFRAG * 64) return;
    int l = idx & 63, f = idx >> 6;
    int lo = (f >= 20);
    int q  = lo ? (f - 20) : (f >> 2);
    int nt = lo ? 2 : (f & 3);
    int n = nt * 16 + (l & 15), o = l >> 4;
    u16 u[8];
    #pragma unroll
    for (int j = 0; j < 8; ++j) {
        int k = q * 32 + o * 8 + j;
        float wv = 0.0f;
        if (k < 144) wv = krec[k * 64 + n];
        else if (k < 153) wv = kin[(k - 144) * 64 + n];
        u16 hi = f2bf(wv);
        u[j] = lo ? f2bf(wv - bf2f(hi)) : hi;
    }
    int4 v;
    v.x = (int)((u32)u[0] | ((u32)u[1] << 16));
    v.y = (int)((u32)u[2] | ((u32)u[3] << 16));
    v.z = (int)((u32)u[4] | ((u32)u[5] << 16));
    v.w = (int)((u32)u[6] | ((u32)u[7] << 16));
    fragbuf[f * 64 + l] = v;
}

// ---------------- fused ConvLSTM step ----------------
// Tile: TY=4 rows x 64 x. 4 waves; wave w owns x-slice w*16..+15, all rows, all 4 gates.
// B-frags from global (L1-resident); LDS = h halo + packed x (27.2 KB) -> 4 blocks/CU.
// Interior blocks (~49%) take a bounds-check-free fast path (block-uniform branch).
__global__ __launch_bounds__(256, 4)
void lstm_step(const u16* __restrict__ xpb, int t,
               const u16* __restrict__ hin,    // [b][y][x][16] bf16
               u16* __restrict__ hout,
               u16* __restrict__ cbuf,         // [b][y][x][16] fp16
               const int4* __restrict__ fragbuf,
               const float* __restrict__ bias) {
    __shared__ __align__(16) u16 sh_h[6 * 66 * PITCH];   // 19,008 B
    __shared__ __align__(16) u16 sxf[2 * 256 * 8];       //  8,192 B  (total 27,200 B)

    const int tid = threadIdx.x;
    const int wv_ = tid >> 6;
    const int l   = tid & 63;
    const int b   = blockIdx.z;
    const int y0  = blockIdx.y * TY;
    const int x0  = blockIdx.x * 64;
    // interior: all staging/epilogue indices provably in-bounds (see derivation)
    const bool fast = (t > 0) & (x0 >= 1) & (x0 <= 173) & (y0 >= 1) & (y0 <= 313);

    // stage h halo (single bf16 plane, 32 B/pixel)
    if (fast) {
        const u16* hb = hin + (((size_t)b * HO + y0 - 1) * WO + x0 - 1) * 16;
        for (int i = tid; i < 6 * 66; i += 256) {
            int hr = i / 66, hx = i - hr * 66;
            const int4* g = (const int4*)&hb[((size_t)hr * WO + hx) * 16];
            u16* d = &sh_h[i * PITCH];
            *(int4*)d = g[0]; *(int4*)(d + 8) = g[1];
        }
    } else {
        for (int i = tid; i < 6 * 66; i += 256) {
            int hr = i / 66, hx = i - hr * 66;
            int gy = y0 - 1 + hr, gx = x0 - 1 + hx;
            bool ok = (t > 0) && gy >= 0 && gy < HO && gx >= 0 && gx < WO;
            int4 v0 = make_int4(0, 0, 0, 0), v1 = v0;
            if (ok) {
                const int4* g = (const int4*)&hin[(((size_t)b * HO + gy) * WO + gx) * 16];
                v0 = g[0]; v1 = g[1];
            }
            u16* d = &sh_h[i * PITCH];
            *(int4*)d = v0; *(int4*)(d + 8) = v1;
        }
    }
    // pack x A-fragments: slot tid = (m = tid>>6, sxi = tid&63). Taps 0..7 -> sxf[0], tap 8 -> sxf[1].
    {
        const int sxi = tid & 63, m = tid >> 6;
        const u16* xs = xpb + (size_t)(b * T_ + t) * HP * WP;
        u16 u[9];
        if (fast) {
            const u16* xr = xs + (size_t)(y0 + m) * WP + x0 + sxi;
            #pragma unroll
            for (int j = 0; j < 9; ++j) u[j] = xr[(j / 3) * WP + (j % 3)];
        } else {
            #pragma unroll
            for (int j = 0; j < 9; ++j) {
                int gy = y0 + m + j / 3, gx = x0 + sxi + j % 3;
                u[j] = (gy < HP && gx < WP) ? xs[(size_t)gy * WP + gx] : (u16)0;
            }
        }
        int4 p;
        p.x = (int)((u32)u[0] | ((u32)u[1] << 16));
        p.y = (int)((u32)u[2] | ((u32)u[3] << 16));
        p.z = (int)((u32)u[4] | ((u32)u[5] << 16));
        p.w = (int)((u32)u[6] | ((u32)u[7] << 16));
        *(int4*)&sxf[tid * 8] = p;
        *(int4*)&sxf[(256 + tid) * 8] = make_int4((int)(u32)u[8], 0, 0, 0);
    }
    __syncthreads();

    float bv[4];
    #pragma unroll
    for (int nt = 0; nt < 4; ++nt) bv[nt] = bias[nt * 16 + (l & 15)];

    f32x4 acc[TY][4];
    #pragma unroll
    for (int m = 0; m < TY; ++m)
        #pragma unroll
        for (int nt = 0; nt < 4; ++nt)
            acc[m][nt] = (f32x4){bv[nt], bv[nt], bv[nt], bv[nt]};

    const int o    = l >> 4;
    const int ci0  = (o & 1) * 8;
    const bool hiH = (l >= 32);
    const int wx   = wv_ * 16 + (l & 15);
    const int4* fbl = fragbuf + l;   // lane's record: fbl[f*64]

    // chunks 0..3 with depth-1 prefetch of the next chunk's hi-frags.
    int4 nb0 = fbl[0 * 64], nb1 = fbl[1 * 64], nb2 = fbl[2 * 64], nb3 = fbl[3 * 64];
    #pragma unroll 1
    for (int q = 0; q < 4; ++q) {
        bf16x8 Bh0 = __builtin_bit_cast(bf16x8, nb0);
        bf16x8 Bh1 = __builtin_bit_cast(bf16x8, nb1);
        bf16x8 Bh2 = __builtin_bit_cast(bf16x8, nb2);
        bf16x8 Bh3 = __builtin_bit_cast(bf16x8, nb3);
        bf16x8 Bl2 = __builtin_bit_cast(bf16x8, fbl[(20 + q) * 64]);
        nb0 = fbl[((q + 1) * 4 + 0) * 64];
        nb1 = fbl[((q + 1) * 4 + 1) * 64];
        nb2 = fbl[((q + 1) * 4 + 2) * 64];
        nb3 = fbl[((q + 1) * 4 + 3) * 64];
        const int tap = 2 * q + (hiH ? 1 : 0);
        const int dy = tap / 3, dx = tap - 3 * dy;
        #pragma unroll
        for (int m = 0; m < TY; ++m) {
            bf16x8 Ah = *(const bf16x8*)&sh_h[((m + dy) * 66 + wx + dx) * PITCH + ci0];
            acc[m][0] = __builtin_amdgcn_mfma_f32_16x16x32_bf16(Ah, Bh0, acc[m][0], 0, 0, 0);
            acc[m][1] = __builtin_amdgcn_mfma_f32_16x16x32_bf16(Ah, Bh1, acc[m][1], 0, 0, 0);
            acc[m][2] = __builtin_amdgcn_mfma_f32_16x16x32_bf16(Ah, Bh2, acc[m][2], 0, 0, 0);
            acc[m][2] = __builtin_amdgcn_mfma_f32_16x16x32_bf16(Ah, Bl2,  acc[m][2], 0, 0, 0);
            acc[m][3] = __builtin_amdgcn_mfma_f32_16x16x32_bf16(Ah, Bh3,  acc[m][3], 0, 0, 0);
        }
    }
    // chunk 4 (hi-frags already prefetched): o=0,1 rec tap8; o=2 x taps 0..7; o=3 x tap8
    {
        bf16x8 Bh0 = __builtin_bit_cast(bf16x8, nb0);
        bf16x8 Bh1 = __builtin_bit_cast(bf16x8, nb1);
        bf16x8 Bh2 = __builtin_bit_cast(bf16x8, nb2);
        bf16x8 Bh3 = __builtin_bit_cast(bf16x8, nb3);
        bf16x8 Bl2 = __builtin_bit_cast(bf16x8, fbl[24 * 64]);
        #pragma unroll
        for (int m = 0; m < TY; ++m) {
            bf16x8 Ah;
            if (!hiH) {
                Ah = *(const bf16x8*)&sh_h[((m + 2) * 66 + wx + 2) * PITCH + ci0];
            } else {
                const int slot = (o == 2 ? 0 : 256) + m * 64 + wx;
                Ah = *(const bf16x8*)&sxf[slot * 8];
            }
            acc[m][0] = __builtin_amdgcn_mfma_f32_16x16x32_bf16(Ah, Bh0, acc[m][0], 0, 0, 0);
            acc[m][1] = __builtin_amdgcn_mfma_f32_16x16x32_bf16(Ah, Bh1, acc[m][1], 0, 0, 0);
            acc[m][2] = __builtin_amdgcn_mfma_f32_16x16x32_bf16(Ah, Bh2, acc[m][2], 0, 0, 0);
            acc[m][2] = __builtin_amdgcn_mfma_f32_16x16x32_bf16(Ah, Bl2,  acc[m][2], 0, 0, 0);
            acc[m][3] = __builtin_amdgcn_mfma_f32_16x16x32_bf16(Ah, Bh3,  acc[m][3], 0, 0, 0);
        }
    }

    // gates + state update. C layout: col = l&15 (channel), row = (l>>4)*4 + r (x offset).
    const int ch = l & 15;
    if (fast) {
        #pragma unroll
        for (int m = 0; m < TY; ++m) {
            size_t rowb = (((size_t)b * HO + y0 + m) * WO + x0 + wv_ * 16 + o * 4) * 16 + ch;
            #pragma unroll
            for (int r = 0; r < 4; ++r) {
                size_t gc = rowb + (size_t)r * 16;
                float co = h2f(cbuf[gc]);
                float zi = acc[m][0][r], zf = acc[m][1][r], zc = acc[m][2][r], zo = acc[m][3][r];
                float cn = fmaf(hsg(zf), co, hsg(zi) * tanh_fast(zc));
                float hn = hsg(zo) * tanh_fast(cn);
                cbuf[gc] = f2h(cn);
                hout[gc] = f2bf(hn);
            }
        }
    } else {
        #pragma unroll
        for (int m = 0; m < TY; ++m) {
            const int y = y0 + m;
            if (y < HO) {
                #pragma unroll
                for (int r = 0; r < 4; ++r) {
                    const int x = x0 + wv_ * 16 + o * 4 + r;
                    if (x < WO) {
                        size_t gc = (((size_t)b * HO + y) * WO + x) * 16 + ch;
                        float co = (t > 0) ? h2f(cbuf[gc]) : 0.0f;
                        float zi = acc[m][0][r], zf = acc[m][1][r], zc = acc[m][2][r], zo = acc[m][3][r];
                        float cn = fmaf(hsg(zf), co, hsg(zi) * tanh_fast(zc));
                        float hn = hsg(zo) * tanh_fast(cn);
                        cbuf[gc] = f2h(cn);
                        hout[gc] = f2bf(hn);
                    }
                }
            }
        }
    }
}

// ---------------- dense ----------------
#define NPX    (HO * WO)                       // 75,684 pixels
#define PCHUNK 512
#define NCHUNK ((NPX + PCHUNK - 1) / PCHUNK)   // 148

__device__ __forceinline__ float dot2(u32 a, float w0, float w1, float s) {
    s = fmaf(bf2f((u16)a), w0, s);
    return fmaf(bf2f((u16)(a >> 16)), w1, s);
}

__global__ void dense1(const u16* __restrict__ h, const float* __restrict__ w,
                       float* __restrict__ partial) {
    int b = blockIdx.y, tid = threadIdx.x;
    const u16* hb = h + (size_t)b * NPX * 16;
    float s = 0.0f;
    #pragma unroll
    for (int pp = 0; pp < 2; ++pp) {
        int px = blockIdx.x * PCHUNK + tid * 2 + pp;
        if (px < NPX) {
            const int4* g = (const int4*)&hb[(size_t)px * 16];
            int4 a0 = g[0], a1 = g[1];
            const float* wp = &w[(size_t)px * 16];
            s = dot2((u32)a0.x, wp[0],  wp[1],  s);
            s = dot2((u32)a0.y, wp[2],  wp[3],  s);
            s = dot2((u32)a0.z, wp[4],  wp[5],  s);
            s = dot2((u32)a0.w, wp[6],  wp[7],  s);
            s = dot2((u32)a1.x, wp[8],  wp[9],  s);
            s = dot2((u32)a1.y, wp[10], wp[11], s);
            s = dot2((u32)a1.z, wp[12], wp[13], s);
            s = dot2((u32)a1.w, wp[14], wp[15], s);
        }
    }
    #pragma unroll
    for (int of = 32; of > 0; of >>= 1) s += __shfl_down(s, of, 64);
    __shared__ float red[4];
    if ((tid & 63) == 0) red[tid >> 6] = s;
    __syncthreads();
    if (tid == 0) partial[b * NCHUNK + blockIdx.x] = red[0] + red[1] + red[2] + red[3];
}

__global__ void dense2(const float* __restrict__ partial, const float* __restrict__ db,
                       float* __restrict__ out) {
    int b = blockIdx.x, tid = threadIdx.x;
    float s = 0.0f;
    for (int i = tid; i < NCHUNK; i += 256) s += partial[b * NCHUNK + i];
    #pragma unroll
    for (int of = 32; of > 0; of >>= 1) s += __shfl_down(s, of, 64);
    __shared__ float red[4];
    if ((tid & 63) == 0) red[tid >> 6] = s;
    __syncthreads();
    if (tid == 0) out[b] = red[0] + red[1] + red[2] + red[3] + db[0];
}

extern "C" void kernel_launch(void* const* d_in, const int* in_sizes, int n_in,
                              void* d_out, int out_size, void* d_ws, size_t ws_size,
                              hipStream_t stream) {
    const float* inputs = (const float*)d_in[0];
    const float* kin    = (const float*)d_in[1];
    const float* krec   = (const float*)d_in[2];
    const float* bias   = (const float*)d_in[3];
    const float* dw     = (const float*)d_in[4];
    const float* db     = (const float*)d_in[5];
    float* out = (float*)d_out;

    const size_t XPN = (size_t)B_ * T_ * HP * WP;   // 9,830,400 u16 (bf16 pooled x)
    const size_t HN  = (size_t)B_ * HO * WO * 16;   // 9,687,552 u16 per h buffer

    u16*   xp   = (u16*)d_ws;
    u16*   h0   = xp + XPN;
    u16*   h1   = h0 + HN;
    u16*   cbuf = h1 + HN;                          // fp16 c state
    int4*  frag = (int4*)(cbuf + HN);               // 25,600 B
    float* part = (float*)(frag + NFRAG * 64);

    {
        int total = B_ * T_ * HP * (WP / 2);
        pool_kernel<<<(total + 255) / 256, 256, 0, stream>>>(inputs, (u32*)xp);
    }
    frag_build<<<(NFRAG * 64 + 255) / 256, 256, 0, stream>>>(krec, kin, frag);

    dim3 grid(4, (HO + TY - 1) / TY, B_);   // 4 x 80 x 8
    for (int t = 0; t < T_; ++t) {
        const u16* hi = (t & 1) ? h1 : h0;
        u16*       ho = (t & 1) ? h0 : h1;
        lstm_step<<<grid, 256, 0, stream>>>(xp, t, hi, ho, cbuf, frag, bias);
    }
    // t=15 (odd) wrote h0
    dense1<<<dim3(NCHUNK, B_), 256, 0, stream>>>(h0, dw, part);
    dense2<<<B_, 256, 0, stream>>>(part, db, out);
}

// Round 13
// 583.459 us; speedup vs baseline: 2.0105x; 1.1373x over previous
//
#include <hip/hip_runtime.h>
#include <hip/hip_bf16.h>
#include <cstdint>

#define B_  8
#define T_  16
#define HIN 640
#define WIN 480
#define HP  320
#define WP  240
#define HO  318
#define WO  238

typedef unsigned short u16;
typedef unsigned int   u32;
typedef __attribute__((ext_vector_type(8))) short bf16x8;
typedef __attribute__((ext_vector_type(4))) float f32x4;

#define TY    4
#define PITCH 24   // halfwords per pixel slot (48 B): b128-aligned, ~2-way banks
#define NFRAG 25   // builder keeps 25; kernel uses the 20 hi frags only

__device__ __forceinline__ u16 f2bf(float f) {          // RNE float->bf16 bits
    u32 u = __float_as_uint(f);
    return (u16)((u + 0x7fffu + ((u >> 16) & 1u)) >> 16);
}
__device__ __forceinline__ float bf2f(u16 u) {
    return __uint_as_float(((u32)u) << 16);
}
__device__ __forceinline__ float h2f(u16 u) {           // fp16 bits -> f32
    _Float16 h = __builtin_bit_cast(_Float16, u);
    return (float)h;
}
__device__ __forceinline__ u16 f2h(float f) {           // f32 -> fp16 bits
    _Float16 h = (_Float16)f;
    return __builtin_bit_cast(u16, h);
}
__device__ __forceinline__ float hsg(float v) {         // med3 clamp
    return __builtin_amdgcn_fmed3f(fmaf(v, 0.2f, 0.5f), 0.0f, 1.0f);
}
// tanh = 1 - 2/(e^{2x}+1): exp overflow -> 1, exp(-inf) -> -1
__device__ __forceinline__ float tanh_fast(float x) {
    float e = __expf(2.0f * x);
    return 1.0f - __fdividef(2.0f, e + 1.0f);
}

// ---------------- MaxPool (1,2,2) -> bf16 ----------------
__global__ void pool_kernel(const float* __restrict__ in, u32* __restrict__ out) {
    int idx = blockIdx.x * 256 + threadIdx.x;
    const int total = B_ * T_ * HP * (WP / 2);
    if (idx >= total) return;
    int xp   = idx % (WP / 2);
    int rest = idx / (WP / 2);
    int y    = rest % HP;
    int bt   = rest / HP;
    const float* src = in + ((size_t)bt * HIN + 2 * y) * WIN + xp * 4;
    float4 a = *(const float4*)src;
    float4 b = *(const float4*)(src + WIN);
    float m0 = fmaxf(fmaxf(a.x, a.y), fmaxf(b.x, b.y));
    float m1 = fmaxf(fmaxf(a.z, a.w), fmaxf(b.z, b.w));
    out[((size_t)bt * HP + y) * (WP / 2) + xp] = (u32)f2bf(m0) | ((u32)f2bf(m1) << 16);
}

// ---------------- weight fragment pre-pack ----------------
// K layout: k = tap*16+ci (k<144 recurrent), k = 144+xtap (k<153 input conv), else 0.
// Frags 0..19: hi plane, f = q*4+nt. Frags 20..24: lo plane (unused by step kernel).
__global__ void frag_build(const float* __restrict__ krec, const float* __restrict__ kin,
                           int4* __restrict__ fragbuf) {
    int idx = blockIdx.x * 256 + threadIdx.x;
    if (idx >= NFRAG * 64) return;
    int l = idx & 63, f = idx >> 6;
    int lo = (f >= 20);
    int q  = lo ? (f - 20) : (f >> 2);
    int nt = lo ? 2 : (f & 3);
    int n = nt * 16 + (l & 15), o = l >> 4;
    u16 u[8];
    #pragma unroll
    for (int j = 0; j < 8; ++j) {
        int k = q * 32 + o * 8 + j;
        float wv = 0.0f;
        if (k < 144) wv = krec[k * 64 + n];
        else if (k < 153) wv = kin[(k - 144) * 64 + n];
        u16 hi = f2bf(wv);
        u[j] = lo ? f2bf(wv - bf2f(hi)) : hi;
    }
    int4 v;
    v.x = (int)((u32)u[0] | ((u32)u[1] << 16));
    v.y = (int)((u32)u[2] | ((u32)u[3] << 16));
    v.z = (int)((u32)u[4] | ((u32)u[5] << 16));
    v.w = (int)((u32)u[6] | ((u32)u[7] << 16));
    fragbuf[f * 64 + l] = v;
}

// ---------------- fused ConvLSTM step ----------------
// Tile: TY=4 rows x 64 x. 4 waves; wave w owns x-slice w*16..+15, all rows, all 4 gates.
// B-frags from global (L1-resident); LDS = h halo + packed x (27.2 KB) -> 4 blocks/CU.
// c loads hoisted before the MFMA section (in flight ~2000 cyc).
__global__ __launch_bounds__(256, 4)
void lstm_step(const u16* __restrict__ xpb, int t,
               const u16* __restrict__ hin,    // [b][y][x][16] bf16
               u16* __restrict__ hout,
               u16* __restrict__ cbuf,         // [b][y][x][16] fp16
               const int4* __restrict__ fragbuf,
               const float* __restrict__ bias) {
    __shared__ __align__(16) u16 sh_h[6 * 66 * PITCH];   // 19,008 B
    __shared__ __align__(16) u16 sxf[2 * 256 * 8];       //  8,192 B  (total 27,200 B)

    const int tid = threadIdx.x;
    const int wv_ = tid >> 6;
    const int l   = tid & 63;
    const int b   = blockIdx.z;
    const int y0  = blockIdx.y * TY;
    const int x0  = blockIdx.x * 64;
    const int o   = l >> 4;
    const int ch  = l & 15;
    // interior: all staging/epilogue indices provably in-bounds
    const bool fast = (t > 0) & (x0 >= 1) & (x0 <= 173) & (y0 >= 1) & (y0 <= 313);

    // stage h halo (single bf16 plane, 32 B/pixel)
    if (fast) {
        const u16* hb = hin + (((size_t)b * HO + y0 - 1) * WO + x0 - 1) * 16;
        for (int i = tid; i < 6 * 66; i += 256) {
            int hr = i / 66, hx = i - hr * 66;
            const int4* g = (const int4*)&hb[((size_t)hr * WO + hx) * 16];
            u16* d = &sh_h[i * PITCH];
            *(int4*)d = g[0]; *(int4*)(d + 8) = g[1];
        }
    } else {
        for (int i = tid; i < 6 * 66; i += 256) {
            int hr = i / 66, hx = i - hr * 66;
            int gy = y0 - 1 + hr, gx = x0 - 1 + hx;
            bool ok = (t > 0) && gy >= 0 && gy < HO && gx >= 0 && gx < WO;
            int4 v0 = make_int4(0, 0, 0, 0), v1 = v0;
            if (ok) {
                const int4* g = (const int4*)&hin[(((size_t)b * HO + gy) * WO + gx) * 16];
                v0 = g[0]; v1 = g[1];
            }
            u16* d = &sh_h[i * PITCH];
            *(int4*)d = v0; *(int4*)(d + 8) = v1;
        }
    }
    // pack x A-fragments: slot tid = (m = tid>>6, sxi = tid&63). Taps 0..7 -> sxf[0], tap 8 -> sxf[1].
    {
        const int sxi = tid & 63, m = tid >> 6;
        const u16* xs = xpb + (size_t)(b * T_ + t) * HP * WP;
        u16 u[9];
        if (fast) {
            const u16* xr = xs + (size_t)(y0 + m) * WP + x0 + sxi;
            #pragma unroll
            for (int j = 0; j < 9; ++j) u[j] = xr[(j / 3) * WP + (j % 3)];
        } else {
            #pragma unroll
            for (int j = 0; j < 9; ++j) {
                int gy = y0 + m + j / 3, gx = x0 + sxi + j % 3;
                u[j] = (gy < HP && gx < WP) ? xs[(size_t)gy * WP + gx] : (u16)0;
            }
        }
        int4 p;
        p.x = (int)((u32)u[0] | ((u32)u[1] << 16));
        p.y = (int)((u32)u[2] | ((u32)u[3] << 16));
        p.z = (int)((u32)u[4] | ((u32)u[5] << 16));
        p.w = (int)((u32)u[6] | ((u32)u[7] << 16));
        *(int4*)&sxf[tid * 8] = p;
        *(int4*)&sxf[(256 + tid) * 8] = make_int4((int)(u32)u[8], 0, 0, 0);
    }
    __syncthreads();

    // ---- early c-load: in flight during the whole MFMA section ----
    u16 cv16[TY][4];
    if (t > 0) {
        if (fast) {
            #pragma unroll
            for (int m = 0; m < TY; ++m) {
                size_t rowb = (((size_t)b * HO + y0 + m) * WO + x0 + wv_ * 16 + o * 4) * 16 + ch;
                #pragma unroll
                for (int r = 0; r < 4; ++r) cv16[m][r] = cbuf[rowb + (size_t)r * 16];
            }
        } else {
            #pragma unroll
            for (int m = 0; m < TY; ++m) {
                const int y = y0 + m;
                #pragma unroll
                for (int r = 0; r < 4; ++r) {
                    const int x = x0 + wv_ * 16 + o * 4 + r;
                    cv16[m][r] = (y < HO && x < WO)
                               ? cbuf[(((size_t)b * HO + y) * WO + x) * 16 + ch] : (u16)0;
                }
            }
        }
    } else {
        #pragma unroll
        for (int m = 0; m < TY; ++m)
            #pragma unroll
            for (int r = 0; r < 4; ++r) cv16[m][r] = 0;
    }

    float bv[4];
    #pragma unroll
    for (int nt = 0; nt < 4; ++nt) bv[nt] = bias[nt * 16 + ch];

    f32x4 acc[TY][4];
    #pragma unroll
    for (int m = 0; m < TY; ++m)
        #pragma unroll
        for (int nt = 0; nt < 4; ++nt)
            acc[m][nt] = (f32x4){bv[nt], bv[nt], bv[nt], bv[nt]};

    const int ci0  = (o & 1) * 8;
    const bool hiH = (l >= 32);
    const int wx   = wv_ * 16 + (l & 15);
    const int4* fbl = fragbuf + l;   // lane's record: fbl[f*64]

    // chunks 0..3 with depth-1 prefetch of the next chunk's frags
    int4 nb0 = fbl[0 * 64], nb1 = fbl[1 * 64], nb2 = fbl[2 * 64], nb3 = fbl[3 * 64];
    #pragma unroll 1
    for (int q = 0; q < 4; ++q) {
        bf16x8 Bh0 = __builtin_bit_cast(bf16x8, nb0);
        bf16x8 Bh1 = __builtin_bit_cast(bf16x8, nb1);
        bf16x8 Bh2 = __builtin_bit_cast(bf16x8, nb2);
        bf16x8 Bh3 = __builtin_bit_cast(bf16x8, nb3);
        nb0 = fbl[((q + 1) * 4 + 0) * 64];
        nb1 = fbl[((q + 1) * 4 + 1) * 64];
        nb2 = fbl[((q + 1) * 4 + 2) * 64];
        nb3 = fbl[((q + 1) * 4 + 3) * 64];
        const int tap = 2 * q + (hiH ? 1 : 0);
        const int dy = tap / 3, dx = tap - 3 * dy;
        #pragma unroll
        for (int m = 0; m < TY; ++m) {
            bf16x8 Ah = *(const bf16x8*)&sh_h[((m + dy) * 66 + wx + dx) * PITCH + ci0];
            acc[m][0] = __builtin_amdgcn_mfma_f32_16x16x32_bf16(Ah, Bh0, acc[m][0], 0, 0, 0);
            acc[m][1] = __builtin_amdgcn_mfma_f32_16x16x32_bf16(Ah, Bh1, acc[m][1], 0, 0, 0);
            acc[m][2] = __builtin_amdgcn_mfma_f32_16x16x32_bf16(Ah, Bh2, acc[m][2], 0, 0, 0);
            acc[m][3] = __builtin_amdgcn_mfma_f32_16x16x32_bf16(Ah, Bh3, acc[m][3], 0, 0, 0);
        }
    }
    // chunk 4 (frags already prefetched): o=0,1 rec tap8; o=2 x taps 0..7; o=3 x tap8
    {
        bf16x8 Bh0 = __builtin_bit_cast(bf16x8, nb0);
        bf16x8 Bh1 = __builtin_bit_cast(bf16x8, nb1);
        bf16x8 Bh2 = __builtin_bit_cast(bf16x8, nb2);
        bf16x8 Bh3 = __builtin_bit_cast(bf16x8, nb3);
        #pragma unroll
        for (int m = 0; m < TY; ++m) {
            bf16x8 Ah;
            if (!hiH) {
                Ah = *(const bf16x8*)&sh_h[((m + 2) * 66 + wx + 2) * PITCH + ci0];
            } else {
                const int slot = (o == 2 ? 0 : 256) + m * 64 + wx;
                Ah = *(const bf16x8*)&sxf[slot * 8];
            }
            acc[m][0] = __builtin_amdgcn_mfma_f32_16x16x32_bf16(Ah, Bh0, acc[m][0], 0, 0, 0);
            acc[m][1] = __builtin_amdgcn_mfma_f32_16x16x32_bf16(Ah, Bh1, acc[m][1], 0, 0, 0);
            acc[m][2] = __builtin_amdgcn_mfma_f32_16x16x32_bf16(Ah, Bh2, acc[m][2], 0, 0, 0);
            acc[m][3] = __builtin_amdgcn_mfma_f32_16x16x32_bf16(Ah, Bh3, acc[m][3], 0, 0, 0);
        }
    }

    // gates + state update. C layout: col = l&15 (channel), row = (l>>4)*4 + r (x offset).
    if (fast) {
        #pragma unroll
        for (int m = 0; m < TY; ++m) {
            size_t rowb = (((size_t)b * HO + y0 + m) * WO + x0 + wv_ * 16 + o * 4) * 16 + ch;
            #pragma unroll
            for (int r = 0; r < 4; ++r) {
                size_t gc = rowb + (size_t)r * 16;
                float co = h2f(cv16[m][r]);
                float zi = acc[m][0][r], zf = acc[m][1][r], zc = acc[m][2][r], zo = acc[m][3][r];
                float cn = fmaf(hsg(zf), co, hsg(zi) * tanh_fast(zc));
                float hn = hsg(zo) * tanh_fast(cn);
                cbuf[gc] = f2h(cn);
                hout[gc] = f2bf(hn);
            }
        }
    } else {
        #pragma unroll
        for (int m = 0; m < TY; ++m) {
            const int y = y0 + m;
            if (y < HO) {
                #pragma unroll
                for (int r = 0; r < 4; ++r) {
                    const int x = x0 + wv_ * 16 + o * 4 + r;
                    if (x < WO) {
                        size_t gc = (((size_t)b * HO + y) * WO + x) * 16 + ch;
                        float co = h2f(cv16[m][r]);
                        float zi = acc[m][0][r], zf = acc[m][1][r], zc = acc[m][2][r], zo = acc[m][3][r];
                        float cn = fmaf(hsg(zf), co, hsg(zi) * tanh_fast(zc));
                        float hn = hsg(zo) * tanh_fast(cn);
                        cbuf[gc] = f2h(cn);
                        hout[gc] = f2bf(hn);
                    }
                }
            }
        }
    }
}

// ---------------- dense ----------------
#define NPX    (HO * WO)                       // 75,684 pixels
#define PCHUNK 512
#define NCHUNK ((NPX + PCHUNK - 1) / PCHUNK)   // 148

__device__ __forceinline__ float dot2(u32 a, float w0, float w1, float s) {
    s = fmaf(bf2f((u16)a), w0, s);
    return fmaf(bf2f((u16)(a >> 16)), w1, s);
}

__global__ void dense1(const u16* __restrict__ h, const float* __restrict__ w,
                       float* __restrict__ partial) {
    int b = blockIdx.y, tid = threadIdx.x;
    const u16* hb = h + (size_t)b * NPX * 16;
    float s = 0.0f;
    #pragma unroll
    for (int pp = 0; pp < 2; ++pp) {
        int px = blockIdx.x * PCHUNK + tid * 2 + pp;
        if (px < NPX) {
            const int4* g = (const int4*)&hb[(size_t)px * 16];
            int4 a0 = g[0], a1 = g[1];
            const float* wp = &w[(size_t)px * 16];
            s = dot2((u32)a0.x, wp[0],  wp[1],  s);
            s = dot2((u32)a0.y, wp[2],  wp[3],  s);
            s = dot2((u32)a0.z, wp[4],  wp[5],  s);
            s = dot2((u32)a0.w, wp[6],  wp[7],  s);
            s = dot2((u32)a1.x, wp[8],  wp[9],  s);
            s = dot2((u32)a1.y, wp[10], wp[11], s);
            s = dot2((u32)a1.z, wp[12], wp[13], s);
            s = dot2((u32)a1.w, wp[14], wp[15], s);
        }
    }
    #pragma unroll
    for (int of = 32; of > 0; of >>= 1) s += __shfl_down(s, of, 64);
    __shared__ float red[4];
    if ((tid & 63) == 0) red[tid >> 6] = s;
    __syncthreads();
    if (tid == 0) partial[b * NCHUNK + blockIdx.x] = red[0] + red[1] + red[2] + red[3];
}

__global__ void dense2(const float* __restrict__ partial, const float* __restrict__ db,
                       float* __restrict__ out) {
    int b = blockIdx.x, tid = threadIdx.x;
    float s = 0.0f;
    for (int i = tid; i < NCHUNK; i += 256) s += partial[b * NCHUNK + i];
    #pragma unroll
    for (int of = 32; of > 0; of >>= 1) s += __shfl_down(s, of, 64);
    __shared__ float red[4];
    if ((tid & 63) == 0) red[tid >> 6] = s;
    __syncthreads();
    if (tid == 0) out[b] = red[0] + red[1] + red[2] + red[3] + db[0];
}

extern "C" void kernel_launch(void* const* d_in, const int* in_sizes, int n_in,
                              void* d_out, int out_size, void* d_ws, size_t ws_size,
                              hipStream_t stream) {
    const float* inputs = (const float*)d_in[0];
    const float* kin    = (const float*)d_in[1];
    const float* krec   = (const float*)d_in[2];
    const float* bias   = (const float*)d_in[3];
    const float* dw     = (const float*)d_in[4];
    const float* db     = (const float*)d_in[5];
    float* out = (float*)d_out;

    const size_t XPN = (size_t)B_ * T_ * HP * WP;   // 9,830,400 u16 (bf16 pooled x)
    const size_t HN  = (size_t)B_ * HO * WO * 16;   // 9,687,552 u16 per h buffer

    u16*   xp   = (u16*)d_ws;
    u16*   h0   = xp + XPN;
    u16*   h1   = h0 + HN;
    u16*   cbuf = h1 + HN;                          // fp16 c state
    int4*  frag = (int4*)(cbuf + HN);               // 25,600 B
    float* part = (float*)(frag + NFRAG * 64);

    {
        int total = B_ * T_ * HP * (WP / 2);
        pool_kernel<<<(total + 255) / 256, 256, 0, stream>>>(inputs, (u32*)xp);
    }
    frag_build<<<(NFRAG * 64 + 255) / 256, 256, 0, stream>>>(krec, kin, frag);

    dim3 grid(4, (HO + TY - 1) / TY, B_);   // 4 x 80 x 8
    for (int t = 0; t < T_; ++t) {
        const u16* hi = (t & 1) ? h1 : h0;
        u16*       ho = (t & 1) ? h0 : h1;
        lstm_step<<<grid, 256, 0, stream>>>(xp, t, hi, ho, cbuf, frag, bias);
    }
    // t=15 (odd) wrote h0
    dense1<<<dim3(NCHUNK, B_), 256, 0, stream>>>(h0, dw, part);
    dense2<<<B_, 256, 0, stream>>>(part, db, out);
}

// Round 14
// 530.668 us; speedup vs baseline: 2.2105x; 1.0995x over previous
//
#include <hip/hip_runtime.h>
#include <hip/hip_bf16.h>
#include <cstdint>

#define B_  8
#define T_  16
#define HIN 640
#define WIN 480
#define HP  320
#define WP  240
#define HO  318
#define WO  238

typedef unsigned short u16;
typedef unsigned int   u32;
typedef __attribute__((ext_vector_type(8))) short bf16x8;
typedef __attribute__((ext_vector_type(4))) float f32x4;

#define TY    4
#define PITCH 24   // halfwords per pixel slot (48 B): b128-aligned, ~2-way banks
#define NFRAG 25
#define NBY   80   // y-tiles
#define NWG   (4 * NBY * B_)   // 2560

__device__ __forceinline__ u16 f2bf(float f) {          // RNE float->bf16 bits
    u32 u = __float_as_uint(f);
    return (u16)((u + 0x7fffu + ((u >> 16) & 1u)) >> 16);
}
__device__ __forceinline__ float bf2f(u16 u) {
    return __uint_as_float(((u32)u) << 16);
}
__device__ __forceinline__ float h2f(u16 u) {           // fp16 bits -> f32
    _Float16 h = __builtin_bit_cast(_Float16, u);
    return (float)h;
}
__device__ __forceinline__ u16 f2h(float f) {           // f32 -> fp16 bits
    _Float16 h = (_Float16)f;
    return __builtin_bit_cast(u16, h);
}
__device__ __forceinline__ float hsg(float v) {         // med3 clamp
    return __builtin_amdgcn_fmed3f(fmaf(v, 0.2f, 0.5f), 0.0f, 1.0f);
}
// tanh = 1 - 2/(e^{2x}+1)
__device__ __forceinline__ float tanh_fast(float x) {
    float e = __expf(2.0f * x);
    return 1.0f - __fdividef(2.0f, e + 1.0f);
}

// ---------------- MaxPool (1,2,2) -> bf16 ----------------
__global__ void pool_kernel(const float* __restrict__ in, u32* __restrict__ out) {
    int idx = blockIdx.x * 256 + threadIdx.x;
    const int total = B_ * T_ * HP * (WP / 2);
    if (idx >= total) return;
    int xp   = idx % (WP / 2);
    int rest = idx / (WP / 2);
    int y    = rest % HP;
    int bt   = rest / HP;
    const float* src = in + ((size_t)bt * HIN + 2 * y) * WIN + xp * 4;
    float4 a = *(const float4*)src;
    float4 b = *(const float4*)(src + WIN);
    float m0 = fmaxf(fmaxf(a.x, a.y), fmaxf(b.x, b.y));
    float m1 = fmaxf(fmaxf(a.z, a.w), fmaxf(b.z, b.w));
    out[((size_t)bt * HP + y) * (WP / 2) + xp] = (u32)f2bf(m0) | ((u32)f2bf(m1) << 16);
}

// ---------------- weight fragment pre-pack ----------------
__global__ void frag_build(const float* __restrict__ krec, const float* __restrict__ kin,
                           int4* __restrict__ fragbuf) {
    int idx = blockIdx.x * 256 + threadIdx.x;
    if (idx >= NFRAG * 64) return;
    int l = idx & 63, f = idx >> 6;
    int lo = (f >= 20);
    int q  = lo ? (f - 20) : (f >> 2);
    int nt = lo ? 2 : (f & 3);
    int n = nt * 16 + (l & 15), o = l >> 4;
    u16 u[8];
    #pragma unroll
    for (int j = 0; j < 8; ++j) {
        int k = q * 32 + o * 8 + j;
        float wv = 0.0f;
        if (k < 144) wv = krec[k * 64 + n];
        else if (k < 153) wv = kin[(k - 144) * 64 + n];
        u16 hi = f2bf(wv);
        u[j] = lo ? f2bf(wv - bf2f(hi)) : hi;
    }
    int4 v;
    v.x = (int)((u32)u[0] | ((u32)u[1] << 16));
    v.y = (int)((u32)u[2] | ((u32)u[3] << 16));
    v.z = (int)((u32)u[4] | ((u32)u[5] << 16));
    v.w = (int)((u32)u[6] | ((u32)u[7] << 16));
    fragbuf[f * 64 + l] = v;
}

// ---------------- fused ConvLSTM step ----------------
// 1D grid 2560, XCD swizzle: b = wgid&7 (each XCD owns one batch), by = wgid>>5,
// bx = (wgid>>3)&3. c in private block-slot layout [newid][tid][16] fp16 (2 int4 r/w).
__global__ __launch_bounds__(256, 4)
void lstm_step(const u16* __restrict__ xpb, int t,
               const u16* __restrict__ hin,    // [b][y][x][16] bf16
               u16* __restrict__ hout,
               u16* __restrict__ cbuf,         // [newid][256][16] fp16
               const int4* __restrict__ fragbuf,
               const float* __restrict__ bias, int lastT) {
    __shared__ __align__(16) u16 sh_h[6 * 66 * PITCH];   // 19,008 B
    __shared__ __align__(16) u16 sxf[2 * 256 * 8];       //  8,192 B

    const int tid  = threadIdx.x;
    const int wgid = blockIdx.x;
    const int b    = wgid & 7;
    const int by   = wgid >> 5;
    const int bx   = (wgid >> 3) & 3;
    const int newid = b * 320 + by * 4 + bx;
    const int wv_ = tid >> 6;
    const int l   = tid & 63;
    const int y0  = by * TY;
    const int x0  = bx * 64;
    const int o   = l >> 4;
    const int ch  = l & 15;
    const bool fast = (t > 0) & (x0 >= 1) & (x0 <= 173) & (y0 >= 1) & (y0 <= 313);

    // stage h halo (single bf16 plane, 32 B/pixel)
    if (fast) {
        const u16* hb = hin + (((size_t)b * HO + y0 - 1) * WO + x0 - 1) * 16;
        for (int i = tid; i < 6 * 66; i += 256) {
            int hr = i / 66, hx = i - hr * 66;
            const int4* g = (const int4*)&hb[((size_t)hr * WO + hx) * 16];
            u16* d = &sh_h[i * PITCH];
            *(int4*)d = g[0]; *(int4*)(d + 8) = g[1];
        }
    } else {
        for (int i = tid; i < 6 * 66; i += 256) {
            int hr = i / 66, hx = i - hr * 66;
            int gy = y0 - 1 + hr, gx = x0 - 1 + hx;
            bool ok = (t > 0) && gy >= 0 && gy < HO && gx >= 0 && gx < WO;
            int4 v0 = make_int4(0, 0, 0, 0), v1 = v0;
            if (ok) {
                const int4* g = (const int4*)&hin[(((size_t)b * HO + gy) * WO + gx) * 16];
                v0 = g[0]; v1 = g[1];
            }
            u16* d = &sh_h[i * PITCH];
            *(int4*)d = v0; *(int4*)(d + 8) = v1;
        }
    }
    // pack x A-fragments
    {
        const int sxi = tid & 63, m = tid >> 6;
        const u16* xs = xpb + (size_t)(b * T_ + t) * HP * WP;
        u16 u[9];
        if (fast) {
            const u16* xr = xs + (size_t)(y0 + m) * WP + x0 + sxi;
            #pragma unroll
            for (int j = 0; j < 9; ++j) u[j] = xr[(j / 3) * WP + (j % 3)];
        } else {
            #pragma unroll
            for (int j = 0; j < 9; ++j) {
                int gy = y0 + m + j / 3, gx = x0 + sxi + j % 3;
                u[j] = (gy < HP && gx < WP) ? xs[(size_t)gy * WP + gx] : (u16)0;
            }
        }
        int4 p;
        p.x = (int)((u32)u[0] | ((u32)u[1] << 16));
        p.y = (int)((u32)u[2] | ((u32)u[3] << 16));
        p.z = (int)((u32)u[4] | ((u32)u[5] << 16));
        p.w = (int)((u32)u[6] | ((u32)u[7] << 16));
        *(int4*)&sxf[tid * 8] = p;
        *(int4*)&sxf[(256 + tid) * 8] = make_int4((int)(u32)u[8], 0, 0, 0);
    }
    __syncthreads();

    // ---- early c-load: 2 dense int4 per thread, in flight through MFMA section ----
    int4 c01 = make_int4(0, 0, 0, 0), c23 = c01;
    if (t > 0) {
        const int4* cp = (const int4*)cbuf + ((size_t)newid * 256 + tid) * 2;
        c01 = cp[0]; c23 = cp[1];
    }

    float bv[4];
    #pragma unroll
    for (int nt = 0; nt < 4; ++nt) bv[nt] = bias[nt * 16 + ch];

    f32x4 acc[TY][4];
    #pragma unroll
    for (int m = 0; m < TY; ++m)
        #pragma unroll
        for (int nt = 0; nt < 4; ++nt)
            acc[m][nt] = (f32x4){bv[nt], bv[nt], bv[nt], bv[nt]};

    const int ci0  = (o & 1) * 8;
    const bool hiH = (l >= 32);
    const int wx   = wv_ * 16 + (l & 15);
    const int4* fbl = fragbuf + l;

    // chunks 0..3 with depth-1 prefetch
    int4 nb0 = fbl[0 * 64], nb1 = fbl[1 * 64], nb2 = fbl[2 * 64], nb3 = fbl[3 * 64];
    #pragma unroll 1
    for (int q = 0; q < 4; ++q) {
        bf16x8 Bh0 = __builtin_bit_cast(bf16x8, nb0);
        bf16x8 Bh1 = __builtin_bit_cast(bf16x8, nb1);
        bf16x8 Bh2 = __builtin_bit_cast(bf16x8, nb2);
        bf16x8 Bh3 = __builtin_bit_cast(bf16x8, nb3);
        nb0 = fbl[((q + 1) * 4 + 0) * 64];
        nb1 = fbl[((q + 1) * 4 + 1) * 64];
        nb2 = fbl[((q + 1) * 4 + 2) * 64];
        nb3 = fbl[((q + 1) * 4 + 3) * 64];
        const int tap = 2 * q + (hiH ? 1 : 0);
        const int dy = tap / 3, dx = tap - 3 * dy;
        #pragma unroll
        for (int m = 0; m < TY; ++m) {
            bf16x8 Ah = *(const bf16x8*)&sh_h[((m + dy) * 66 + wx + dx) * PITCH + ci0];
            acc[m][0] = __builtin_amdgcn_mfma_f32_16x16x32_bf16(Ah, Bh0, acc[m][0], 0, 0, 0);
            acc[m][1] = __builtin_amdgcn_mfma_f32_16x16x32_bf16(Ah, Bh1, acc[m][1], 0, 0, 0);
            acc[m][2] = __builtin_amdgcn_mfma_f32_16x16x32_bf16(Ah, Bh2, acc[m][2], 0, 0, 0);
            acc[m][3] = __builtin_amdgcn_mfma_f32_16x16x32_bf16(Ah, Bh3, acc[m][3], 0, 0, 0);
        }
    }
    // chunk 4
    {
        bf16x8 Bh0 = __builtin_bit_cast(bf16x8, nb0);
        bf16x8 Bh1 = __builtin_bit_cast(bf16x8, nb1);
        bf16x8 Bh2 = __builtin_bit_cast(bf16x8, nb2);
        bf16x8 Bh3 = __builtin_bit_cast(bf16x8, nb3);
        #pragma unroll
        for (int m = 0; m < TY; ++m) {
            bf16x8 Ah;
            if (!hiH) {
                Ah = *(const bf16x8*)&sh_h[((m + 2) * 66 + wx + 2) * PITCH + ci0];
            } else {
                const int slot = (o == 2 ? 0 : 256) + m * 64 + wx;
                Ah = *(const bf16x8*)&sxf[slot * 8];
            }
            acc[m][0] = __builtin_amdgcn_mfma_f32_16x16x32_bf16(Ah, Bh0, acc[m][0], 0, 0, 0);
            acc[m][1] = __builtin_amdgcn_mfma_f32_16x16x32_bf16(Ah, Bh1, acc[m][1], 0, 0, 0);
            acc[m][2] = __builtin_amdgcn_mfma_f32_16x16x32_bf16(Ah, Bh2, acc[m][2], 0, 0, 0);
            acc[m][3] = __builtin_amdgcn_mfma_f32_16x16x32_bf16(Ah, Bh3, acc[m][3], 0, 0, 0);
        }
    }

    // unpack c (all indices compile-time)
    u16 cl[16];
    {
        u32 d;
        d = (u32)c01.x; cl[0] = (u16)d;  cl[1] = (u16)(d >> 16);
        d = (u32)c01.y; cl[2] = (u16)d;  cl[3] = (u16)(d >> 16);
        d = (u32)c01.z; cl[4] = (u16)d;  cl[5] = (u16)(d >> 16);
        d = (u32)c01.w; cl[6] = (u16)d;  cl[7] = (u16)(d >> 16);
        d = (u32)c23.x; cl[8] = (u16)d;  cl[9] = (u16)(d >> 16);
        d = (u32)c23.y; cl[10] = (u16)d; cl[11] = (u16)(d >> 16);
        d = (u32)c23.z; cl[12] = (u16)d; cl[13] = (u16)(d >> 16);
        d = (u32)c23.w; cl[14] = (u16)d; cl[15] = (u16)(d >> 16);
    }
    u16 cs[16];

    // gates + state update. C layout: col = ch, row = (l>>4)*4 + r (x offset).
    if (fast) {
        #pragma unroll
        for (int m = 0; m < TY; ++m) {
            size_t rowb = (((size_t)b * HO + y0 + m) * WO + x0 + wv_ * 16 + o * 4) * 16 + ch;
            #pragma unroll
            for (int r = 0; r < 4; ++r) {
                float co = h2f(cl[m * 4 + r]);
                float zi = acc[m][0][r], zf = acc[m][1][r], zc = acc[m][2][r], zo = acc[m][3][r];
                float cn = fmaf(hsg(zf), co, hsg(zi) * tanh_fast(zc));
                float hn = hsg(zo) * tanh_fast(cn);
                cs[m * 4 + r] = f2h(cn);
                hout[rowb + (size_t)r * 16] = f2bf(hn);
            }
        }
    } else {
        #pragma unroll
        for (int m = 0; m < TY; ++m) {
            const int y = y0 + m;
            #pragma unroll
            for (int r = 0; r < 4; ++r) {
                const int x = x0 + wv_ * 16 + o * 4 + r;
                float co = h2f(cl[m * 4 + r]);
                float zi = acc[m][0][r], zf = acc[m][1][r], zc = acc[m][2][r], zo = acc[m][3][r];
                float cn = fmaf(hsg(zf), co, hsg(zi) * tanh_fast(zc));
                float hn = hsg(zo) * tanh_fast(cn);
                cs[m * 4 + r] = f2h(cn);
                if (y < HO && x < WO)
                    hout[(((size_t)b * HO + y) * WO + x) * 16 + ch] = f2bf(hn);
            }
        }
    }
    if (!lastT) {
        int4 o01, o23;
        o01.x = (int)((u32)cs[0]  | ((u32)cs[1]  << 16));
        o01.y = (int)((u32)cs[2]  | ((u32)cs[3]  << 16));
        o01.z = (int)((u32)cs[4]  | ((u32)cs[5]  << 16));
        o01.w = (int)((u32)cs[6]  | ((u32)cs[7]  << 16));
        o23.x = (int)((u32)cs[8]  | ((u32)cs[9]  << 16));
        o23.y = (int)((u32)cs[10] | ((u32)cs[11] << 16));
        o23.z = (int)((u32)cs[12] | ((u32)cs[13] << 16));
        o23.w = (int)((u32)cs[14] | ((u32)cs[15] << 16));
        int4* cp = (int4*)cbuf + ((size_t)newid * 256 + tid) * 2;
        cp[0] = o01; cp[1] = o23;
    }
}

// ---------------- dense ----------------
#define NPX    (HO * WO)
#define PCHUNK 512
#define NCHUNK ((NPX + PCHUNK - 1) / PCHUNK)   // 148

__device__ __forceinline__ float dot2(u32 a, float w0, float w1, float s) {
    s = fmaf(bf2f((u16)a), w0, s);
    return fmaf(bf2f((u16)(a >> 16)), w1, s);
}

__global__ void dense1(const u16* __restrict__ h, const float* __restrict__ w,
                       float* __restrict__ partial) {
    int b = blockIdx.y, tid = threadIdx.x;
    const u16* hb = h + (size_t)b * NPX * 16;
    float s = 0.0f;
    #pragma unroll
    for (int pp = 0; pp < 2; ++pp) {
        int px = blockIdx.x * PCHUNK + tid * 2 + pp;
        if (px < NPX) {
            const int4* g = (const int4*)&hb[(size_t)px * 16];
            int4 a0 = g[0], a1 = g[1];
            const float4* wp = (const float4*)&w[(size_t)px * 16];
            float4 w0 = wp[0], w1 = wp[1], w2 = wp[2], w3 = wp[3];
            s = dot2((u32)a0.x, w0.x, w0.y, s);
            s = dot2((u32)a0.y, w0.z, w0.w, s);
            s = dot2((u32)a0.z, w1.x, w1.y, s);
            s = dot2((u32)a0.w, w1.z, w1.w, s);
            s = dot2((u32)a1.x, w2.x, w2.y, s);
            s = dot2((u32)a1.y, w2.z, w2.w, s);
            s = dot2((u32)a1.z, w3.x, w3.y, s);
            s = dot2((u32)a1.w, w3.z, w3.w, s);
        }
    }
    #pragma unroll
    for (int of = 32; of > 0; of >>= 1) s += __shfl_down(s, of, 64);
    __shared__ float red[4];
    if ((tid & 63) == 0) red[tid >> 6] = s;
    __syncthreads();
    if (tid == 0) partial[b * NCHUNK + blockIdx.x] = red[0] + red[1] + red[2] + red[3];
}

__global__ void dense2(const float* __restrict__ partial, const float* __restrict__ db,
                       float* __restrict__ out) {
    int b = blockIdx.x, tid = threadIdx.x;
    float s = 0.0f;
    for (int i = tid; i < NCHUNK; i += 256) s += partial[b * NCHUNK + i];
    #pragma unroll
    for (int of = 32; of > 0; of >>= 1) s += __shfl_down(s, of, 64);
    __shared__ float red[4];
    if ((tid & 63) == 0) red[tid >> 6] = s;
    __syncthreads();
    if (tid == 0) out[b] = red[0] + red[1] + red[2] + red[3] + db[0];
}

extern "C" void kernel_launch(void* const* d_in, const int* in_sizes, int n_in,
                              void* d_out, int out_size, void* d_ws, size_t ws_size,
                              hipStream_t stream) {
    const float* inputs = (const float*)d_in[0];
    const float* kin    = (const float*)d_in[1];
    const float* krec   = (const float*)d_in[2];
    const float* bias   = (const float*)d_in[3];
    const float* dw     = (const float*)d_in[4];
    const float* db     = (const float*)d_in[5];
    float* out = (float*)d_out;

    const size_t XPN = (size_t)B_ * T_ * HP * WP;   // u16 pooled x
    const size_t HN  = (size_t)B_ * HO * WO * 16;   // u16 per h buffer
    const size_t CN  = (size_t)NWG * 256 * 16;      // u16 c (block-slot layout)

    u16*   xp   = (u16*)d_ws;
    u16*   h0   = xp + XPN;
    u16*   h1   = h0 + HN;
    u16*   cbuf = h1 + HN;
    int4*  frag = (int4*)(cbuf + CN);               // 25,600 B
    float* part = (float*)(frag + NFRAG * 64);

    {
        int total = B_ * T_ * HP * (WP / 2);
        pool_kernel<<<(total + 255) / 256, 256, 0, stream>>>(inputs, (u32*)xp);
    }
    frag_build<<<(NFRAG * 64 + 255) / 256, 256, 0, stream>>>(krec, kin, frag);

    for (int t = 0; t < T_; ++t) {
        const u16* hi = (t & 1) ? h1 : h0;
        u16*       ho = (t & 1) ? h0 : h1;
        lstm_step<<<NWG, 256, 0, stream>>>(xp, t, hi, ho, cbuf, frag, bias, (t == T_ - 1));
    }
    // t=15 (odd) wrote h0
    dense1<<<dim3(NCHUNK, B_), 256, 0, stream>>>(h0, dw, part);
    dense2<<<B_, 256, 0, stream>>>(part, db, out);
}

// Round 15
// 520.971 us; speedup vs baseline: 2.2516x; 1.0186x over previous
//
#include <hip/hip_runtime.h>
#include <hip/hip_bf16.h>
#include <cstdint>

#define B_  8
#define T_  16
#define HIN 640
#define WIN 480
#define HP  320
#define WP  240
#define HO  318
#define WO  238

typedef unsigned short u16;
typedef unsigned int   u32;
typedef __attribute__((ext_vector_type(8))) short bf16x8;
typedef __attribute__((ext_vector_type(4))) float f32x4;

#define TY    4
#define PITCH 16   // halfwords per pixel slot (32 B, contiguous -> global_load_lds OK)
#define NFRAG 25
#define NBY   80   // y-tiles
#define NWG   (4 * NBY * B_)   // 2560

__device__ __forceinline__ u16 f2bf(float f) {          // RNE float->bf16 bits
    u32 u = __float_as_uint(f);
    return (u16)((u + 0x7fffu + ((u >> 16) & 1u)) >> 16);
}
__device__ __forceinline__ float bf2f(u16 u) {
    return __uint_as_float(((u32)u) << 16);
}
__device__ __forceinline__ float h2f(u16 u) {           // fp16 bits -> f32
    _Float16 h = __builtin_bit_cast(_Float16, u);
    return (float)h;
}
__device__ __forceinline__ u16 f2h(float f) {           // f32 -> fp16 bits
    _Float16 h = (_Float16)f;
    return __builtin_bit_cast(u16, h);
}
__device__ __forceinline__ float hsg(float v) {         // med3 clamp
    return __builtin_amdgcn_fmed3f(fmaf(v, 0.2f, 0.5f), 0.0f, 1.0f);
}
// tanh = 1 - 2/(e^{2x}+1)
__device__ __forceinline__ float tanh_fast(float x) {
    float e = __expf(2.0f * x);
    return 1.0f - __fdividef(2.0f, e + 1.0f);
}

// ---------------- MaxPool (1,2,2) -> bf16 ----------------
__global__ void pool_kernel(const float* __restrict__ in, u32* __restrict__ out) {
    int idx = blockIdx.x * 256 + threadIdx.x;
    const int total = B_ * T_ * HP * (WP / 2);
    if (idx >= total) return;
    int xp   = idx % (WP / 2);
    int rest = idx / (WP / 2);
    int y    = rest % HP;
    int bt   = rest / HP;
    const float* src = in + ((size_t)bt * HIN + 2 * y) * WIN + xp * 4;
    float4 a = *(const float4*)src;
    float4 b = *(const float4*)(src + WIN);
    float m0 = fmaxf(fmaxf(a.x, a.y), fmaxf(b.x, b.y));
    float m1 = fmaxf(fmaxf(a.z, a.w), fmaxf(b.z, b.w));
    out[((size_t)bt * HP + y) * (WP / 2) + xp] = (u32)f2bf(m0) | ((u32)f2bf(m1) << 16);
}

// ---------------- weight fragment pre-pack ----------------
__global__ void frag_build(const float* __restrict__ krec, const float* __restrict__ kin,
                           int4* __restrict__ fragbuf) {
    int idx = blockIdx.x * 256 + threadIdx.x;
    if (idx >= NFRAG * 64) return;
    int l = idx & 63, f = idx >> 6;
    int lo = (f >= 20);
    int q  = lo ? (f - 20) : (f >> 2);
    int nt = lo ? 2 : (f & 3);
    int n = nt * 16 + (l & 15), o = l >> 4;
    u16 u[8];
    #pragma unroll
    for (int j = 0; j < 8; ++j) {
        int k = q * 32 + o * 8 + j;
        float wv = 0.0f;
        if (k < 144) wv = krec[k * 64 + n];
        else if (k < 153) wv = kin[(k - 144) * 64 + n];
        u16 hi = f2bf(wv);
        u[j] = lo ? f2bf(wv - bf2f(hi)) : hi;
    }
    int4 v;
    v.x = (int)((u32)u[0] | ((u32)u[1] << 16));
    v.y = (int)((u32)u[2] | ((u32)u[3] << 16));
    v.z = (int)((u32)u[4] | ((u32)u[5] << 16));
    v.w = (int)((u32)u[6] | ((u32)u[7] << 16));
    fragbuf[f * 64 + l] = v;
}

// ---------------- fused ConvLSTM step ----------------
// 1D grid 2560, XCD swizzle: b = wgid&7 (each XCD owns one batch), by = wgid>>5,
// bx = (wgid>>3)&3. c in private block-slot layout [newid][tid][16] fp16.
// Fast-path h-halo staging: global_load_lds (no VGPR round trip).
__global__ __launch_bounds__(256, 4)
void lstm_step(const u16* __restrict__ xpb, int t,
               const u16* __restrict__ hin,    // [b][y][x][16] bf16
               u16* __restrict__ hout,
               u16* __restrict__ cbuf,         // [newid][256][16] fp16
               const int4* __restrict__ fragbuf,
               const float* __restrict__ bias, int lastT) {
    __shared__ __align__(16) u16 sh_h[6 * 66 * PITCH];   // 12,672 B
    __shared__ __align__(16) u16 sxf[2 * 256 * 8];       //  8,192 B (total 20,864)

    const int tid  = threadIdx.x;
    const int wgid = blockIdx.x;
    const int b    = wgid & 7;
    const int by   = wgid >> 5;
    const int bx   = (wgid >> 3) & 3;
    const int newid = b * 320 + by * 4 + bx;
    const int wv_ = tid >> 6;
    const int l   = tid & 63;
    const int y0  = by * TY;
    const int x0  = bx * 64;
    const int o   = l >> 4;
    const int ch  = l & 15;
    const bool fast = (t > 0) & (x0 >= 1) & (x0 <= 173) & (y0 >= 1) & (y0 <= 313);

    // stage h halo (6x66 px, 32 B/px contiguous)
    if (fast) {
        // 792 16-B units; unit u = (px = u>>1, half = u&1); dest = sh_h + u*16 B.
        const u16* hb = hin + (((size_t)b * HO + y0 - 1) * WO + x0 - 1) * 16;
        #pragma unroll
        for (int k = 0; k < 4; ++k) {
            const int unit = k * 256 + tid;
            if (unit < 792) {
                const int px = unit >> 1, half = unit & 1;
                const int hr = px / 66, hx = px - hr * 66;
                const u16* g = hb + ((size_t)hr * WO + hx) * 16 + half * 8;
                u16* lp = sh_h + (size_t)(k * 256 + wv_ * 64) * 8;   // wave-uniform base
                __builtin_amdgcn_global_load_lds(
                    (const __attribute__((address_space(1))) void*)g,
                    (__attribute__((address_space(3))) void*)lp, 16, 0, 0);
            }
        }
    } else {
        for (int i = tid; i < 6 * 66; i += 256) {
            int hr = i / 66, hx = i - hr * 66;
            int gy = y0 - 1 + hr, gx = x0 - 1 + hx;
            bool ok = (t > 0) && gy >= 0 && gy < HO && gx >= 0 && gx < WO;
            int4 v0 = make_int4(0, 0, 0, 0), v1 = v0;
            if (ok) {
                const int4* g = (const int4*)&hin[(((size_t)b * HO + gy) * WO + gx) * 16];
                v0 = g[0]; v1 = g[1];
            }
            u16* d = &sh_h[i * PITCH];
            *(int4*)d = v0; *(int4*)(d + 8) = v1;
        }
    }

    // ---- early c-load: 2 dense int4 per thread, in flight through MFMA section ----
    int4 c01 = make_int4(0, 0, 0, 0), c23 = c01;
    if (t > 0) {
        const int4* cp = (const int4*)cbuf + ((size_t)newid * 256 + tid) * 2;
        c01 = cp[0]; c23 = cp[1];
    }

    // pack x A-fragments
    {
        const int sxi = tid & 63, m = tid >> 6;
        const u16* xs = xpb + (size_t)(b * T_ + t) * HP * WP;
        u16 u[9];
        if (fast) {
            const u16* xr = xs + (size_t)(y0 + m) * WP + x0 + sxi;
            #pragma unroll
            for (int j = 0; j < 9; ++j) u[j] = xr[(j / 3) * WP + (j % 3)];
        } else {
            #pragma unroll
            for (int j = 0; j < 9; ++j) {
                int gy = y0 + m + j / 3, gx = x0 + sxi + j % 3;
                u[j] = (gy < HP && gx < WP) ? xs[(size_t)gy * WP + gx] : (u16)0;
            }
        }
        int4 p;
        p.x = (int)((u32)u[0] | ((u32)u[1] << 16));
        p.y = (int)((u32)u[2] | ((u32)u[3] << 16));
        p.z = (int)((u32)u[4] | ((u32)u[5] << 16));
        p.w = (int)((u32)u[6] | ((u32)u[7] << 16));
        *(int4*)&sxf[tid * 8] = p;
        *(int4*)&sxf[(256 + tid) * 8] = make_int4((int)(u32)u[8], 0, 0, 0);
    }
    __syncthreads();

    float bv[4];
    #pragma unroll
    for (int nt = 0; nt < 4; ++nt) bv[nt] = bias[nt * 16 + ch];

    f32x4 acc[TY][4];
    #pragma unroll
    for (int m = 0; m < TY; ++m)
        #pragma unroll
        for (int nt = 0; nt < 4; ++nt)
            acc[m][nt] = (f32x4){bv[nt], bv[nt], bv[nt], bv[nt]};

    const int ci0  = (o & 1) * 8;
    const bool hiH = (l >= 32);
    const int wx   = wv_ * 16 + (l & 15);
    const int4* fbl = fragbuf + l;

    // chunks 0..3 with depth-1 prefetch
    int4 nb0 = fbl[0 * 64], nb1 = fbl[1 * 64], nb2 = fbl[2 * 64], nb3 = fbl[3 * 64];
    #pragma unroll 1
    for (int q = 0; q < 4; ++q) {
        bf16x8 Bh0 = __builtin_bit_cast(bf16x8, nb0);
        bf16x8 Bh1 = __builtin_bit_cast(bf16x8, nb1);
        bf16x8 Bh2 = __builtin_bit_cast(bf16x8, nb2);
        bf16x8 Bh3 = __builtin_bit_cast(bf16x8, nb3);
        nb0 = fbl[((q + 1) * 4 + 0) * 64];
        nb1 = fbl[((q + 1) * 4 + 1) * 64];
        nb2 = fbl[((q + 1) * 4 + 2) * 64];
        nb3 = fbl[((q + 1) * 4 + 3) * 64];
        const int tap = 2 * q + (hiH ? 1 : 0);
        const int dy = tap / 3, dx = tap - 3 * dy;
        #pragma unroll
        for (int m = 0; m < TY; ++m) {
            bf16x8 Ah = *(const bf16x8*)&sh_h[((m + dy) * 66 + wx + dx) * PITCH + ci0];
            acc[m][0] = __builtin_amdgcn_mfma_f32_16x16x32_bf16(Ah, Bh0, acc[m][0], 0, 0, 0);
            acc[m][1] = __builtin_amdgcn_mfma_f32_16x16x32_bf16(Ah, Bh1, acc[m][1], 0, 0, 0);
            acc[m][2] = __builtin_amdgcn_mfma_f32_16x16x32_bf16(Ah, Bh2, acc[m][2], 0, 0, 0);
            acc[m][3] = __builtin_amdgcn_mfma_f32_16x16x32_bf16(Ah, Bh3, acc[m][3], 0, 0, 0);
        }
    }
    // chunk 4
    {
        bf16x8 Bh0 = __builtin_bit_cast(bf16x8, nb0);
        bf16x8 Bh1 = __builtin_bit_cast(bf16x8, nb1);
        bf16x8 Bh2 = __builtin_bit_cast(bf16x8, nb2);
        bf16x8 Bh3 = __builtin_bit_cast(bf16x8, nb3);
        #pragma unroll
        for (int m = 0; m < TY; ++m) {
            bf16x8 Ah;
            if (!hiH) {
                Ah = *(const bf16x8*)&sh_h[((m + 2) * 66 + wx + 2) * PITCH + ci0];
            } else {
                const int slot = (o == 2 ? 0 : 256) + m * 64 + wx;
                Ah = *(const bf16x8*)&sxf[slot * 8];
            }
            acc[m][0] = __builtin_amdgcn_mfma_f32_16x16x32_bf16(Ah, Bh0, acc[m][0], 0, 0, 0);
            acc[m][1] = __builtin_amdgcn_mfma_f32_16x16x32_bf16(Ah, Bh1, acc[m][1], 0, 0, 0);
            acc[m][2] = __builtin_amdgcn_mfma_f32_16x16x32_bf16(Ah, Bh2, acc[m][2], 0, 0, 0);
            acc[m][3] = __builtin_amdgcn_mfma_f32_16x16x32_bf16(Ah, Bh3, acc[m][3], 0, 0, 0);
        }
    }

    // unpack c (all indices compile-time)
    u16 cl[16];
    {
        u32 d;
        d = (u32)c01.x; cl[0] = (u16)d;  cl[1] = (u16)(d >> 16);
        d = (u32)c01.y; cl[2] = (u16)d;  cl[3] = (u16)(d >> 16);
        d = (u32)c01.z; cl[4] = (u16)d;  cl[5] = (u16)(d >> 16);
        d = (u32)c01.w; cl[6] = (u16)d;  cl[7] = (u16)(d >> 16);
        d = (u32)c23.x; cl[8] = (u16)d;  cl[9] = (u16)(d >> 16);
        d = (u32)c23.y; cl[10] = (u16)d; cl[11] = (u16)(d >> 16);
        d = (u32)c23.z; cl[12] = (u16)d; cl[13] = (u16)(d >> 16);
        d = (u32)c23.w; cl[14] = (u16)d; cl[15] = (u16)(d >> 16);
    }
    u16 cs[16];

    // gates + state update. C layout: col = ch, row = (l>>4)*4 + r (x offset).
    if (fast) {
        #pragma unroll
        for (int m = 0; m < TY; ++m) {
            size_t rowb = (((size_t)b * HO + y0 + m) * WO + x0 + wv_ * 16 + o * 4) * 16 + ch;
            #pragma unroll
            for (int r = 0; r < 4; ++r) {
                float co = h2f(cl[m * 4 + r]);
                float zi = acc[m][0][r], zf = acc[m][1][r], zc = acc[m][2][r], zo = acc[m][3][r];
                float cn = fmaf(hsg(zf), co, hsg(zi) * tanh_fast(zc));
                float hn = hsg(zo) * tanh_fast(cn);
                cs[m * 4 + r] = f2h(cn);
                hout[rowb + (size_t)r * 16] = f2bf(hn);
            }
        }
    } else {
        #pragma unroll
        for (int m = 0; m < TY; ++m) {
            const int y = y0 + m;
            #pragma unroll
            for (int r = 0; r < 4; ++r) {
                const int x = x0 + wv_ * 16 + o * 4 + r;
                float co = h2f(cl[m * 4 + r]);
                float zi = acc[m][0][r], zf = acc[m][1][r], zc = acc[m][2][r], zo = acc[m][3][r];
                float cn = fmaf(hsg(zf), co, hsg(zi) * tanh_fast(zc));
                float hn = hsg(zo) * tanh_fast(cn);
                cs[m * 4 + r] = f2h(cn);
                if (y < HO && x < WO)
                    hout[(((size_t)b * HO + y) * WO + x) * 16 + ch] = f2bf(hn);
            }
        }
    }
    if (!lastT) {
        int4 o01, o23;
        o01.x = (int)((u32)cs[0]  | ((u32)cs[1]  << 16));
        o01.y = (int)((u32)cs[2]  | ((u32)cs[3]  << 16));
        o01.z = (int)((u32)cs[4]  | ((u32)cs[5]  << 16));
        o01.w = (int)((u32)cs[6]  | ((u32)cs[7]  << 16));
        o23.x = (int)((u32)cs[8]  | ((u32)cs[9]  << 16));
        o23.y = (int)((u32)cs[10] | ((u32)cs[11] << 16));
        o23.z = (int)((u32)cs[12] | ((u32)cs[13] << 16));
        o23.w = (int)((u32)cs[14] | ((u32)cs[15] << 16));
        int4* cp = (int4*)cbuf + ((size_t)newid * 256 + tid) * 2;
        cp[0] = o01; cp[1] = o23;
    }
}

// ---------------- dense ----------------
#define NPX    (HO * WO)
#define PCHUNK 512
#define NCHUNK ((NPX + PCHUNK - 1) / PCHUNK)   // 148

__device__ __forceinline__ float dot2(u32 a, float w0, float w1, float s) {
    s = fmaf(bf2f((u16)a), w0, s);
    return fmaf(bf2f((u16)(a >> 16)), w1, s);
}

__global__ void dense1(const u16* __restrict__ h, const float* __restrict__ w,
                       float* __restrict__ partial) {
    int b = blockIdx.y, tid = threadIdx.x;
    const u16* hb = h + (size_t)b * NPX * 16;
    float s = 0.0f;
    #pragma unroll
    for (int pp = 0; pp < 2; ++pp) {
        int px = blockIdx.x * PCHUNK + tid * 2 + pp;
        if (px < NPX) {
            const int4* g = (const int4*)&hb[(size_t)px * 16];
            int4 a0 = g[0], a1 = g[1];
            const float4* wp = (const float4*)&w[(size_t)px * 16];
            float4 w0 = wp[0], w1 = wp[1], w2 = wp[2], w3 = wp[3];
            s = dot2((u32)a0.x, w0.x, w0.y, s);
            s = dot2((u32)a0.y, w0.z, w0.w, s);
            s = dot2((u32)a0.z, w1.x, w1.y, s);
            s = dot2((u32)a0.w, w1.z, w1.w, s);
            s = dot2((u32)a1.x, w2.x, w2.y, s);
            s = dot2((u32)a1.y, w2.z, w2.w, s);
            s = dot2((u32)a1.z, w3.x, w3.y, s);
            s = dot2((u32)a1.w, w3.z, w3.w, s);
        }
    }
    #pragma unroll
    for (int of = 32; of > 0; of >>= 1) s += __shfl_down(s, of, 64);
    __shared__ float red[4];
    if ((tid & 63) == 0) red[tid >> 6] = s;
    __syncthreads();
    if (tid == 0) partial[b * NCHUNK + blockIdx.x] = red[0] + red[1] + red[2] + red[3];
}

__global__ void dense2(const float* __restrict__ partial, const float* __restrict__ db,
                       float* __restrict__ out) {
    int b = blockIdx.x, tid = threadIdx.x;
    float s = 0.0f;
    for (int i = tid; i < NCHUNK; i += 256) s += partial[b * NCHUNK + i];
    #pragma unroll
    for (int of = 32; of > 0; of >>= 1) s += __shfl_down(s, of, 64);
    __shared__ float red[4];
    if ((tid & 63) == 0) red[tid >> 6] = s;
    __syncthreads();
    if (tid == 0) out[b] = red[0] + red[1] + red[2] + red[3] + db[0];
}

extern "C" void kernel_launch(void* const* d_in, const int* in_sizes, int n_in,
                              void* d_out, int out_size, void* d_ws, size_t ws_size,
                              hipStream_t stream) {
    const float* inputs = (const float*)d_in[0];
    const float* kin    = (const float*)d_in[1];
    const float* krec   = (const float*)d_in[2];
    const float* bias   = (const float*)d_in[3];
    const float* dw     = (const float*)d_in[4];
    const float* db     = (const float*)d_in[5];
    float* out = (float*)d_out;

    const size_t XPN = (size_t)B_ * T_ * HP * WP;   // u16 pooled x
    const size_t HN  = (size_t)B_ * HO * WO * 16;   // u16 per h buffer
    const size_t CN  = (size_t)NWG * 256 * 16;      // u16 c (block-slot layout)

    u16*   xp   = (u16*)d_ws;
    u16*   h0   = xp + XPN;
    u16*   h1   = h0 + HN;
    u16*   cbuf = h1 + HN;
    int4*  frag = (int4*)(cbuf + CN);               // 25,600 B
    float* part = (float*)(frag + NFRAG * 64);

    {
        int total = B_ * T_ * HP * (WP / 2);
        pool_kernel<<<(total + 255) / 256, 256, 0, stream>>>(inputs, (u32*)xp);
    }
    frag_build<<<(NFRAG * 64 + 255) / 256, 256, 0, stream>>>(krec, kin, frag);

    for (int t = 0; t < T_; ++t) {
        const u16* hi = (t & 1) ? h1 : h0;
        u16*       ho = (t & 1) ? h0 : h1;
        lstm_step<<<NWG, 256, 0, stream>>>(xp, t, hi, ho, cbuf, frag, bias, (t == T_ - 1));
    }
    // t=15 (odd) wrote h0
    dense1<<<dim3(NCHUNK, B_), 256, 0, stream>>>(h0, dw, part);
    dense2<<<B_, 256, 0, stream>>>(part, db, out);
}